// Round 9
// baseline (339.720 us; speedup 1.0000x reference)
//
#include <hip/hip_runtime.h>

#define NN 4096
#define NHEADS 4
#define HID 64
#define INDIM 256

using short8 = __attribute__((ext_vector_type(8))) short;
using f32x4  = __attribute__((ext_vector_type(4))) float;

union f32u { float f; unsigned int u; };
union i4s8 { int4 i; short8 s; };

__device__ __forceinline__ float bf2f(unsigned short s) {
  f32u x; x.u = ((unsigned int)s) << 16; return x.f;
}
__device__ __forceinline__ unsigned short f2bf(float f) {
  f32u x; x.f = f;
  unsigned int r = x.u + 0x7fffu + ((x.u >> 16) & 1u);
  return (unsigned short)(r >> 16);
}
// packed f32x2 -> bf16x2 (RNE, same as f2bf) in one instruction
__device__ __forceinline__ unsigned int cvtpk(float lo, float hi) {
  unsigned int r;
  asm("v_cvt_pk_bf16_f32 %0, %1, %2" : "=v"(r) : "v"(lo), "v"(hi));
  return r;
}

// overloaded external-input loaders
__device__ __forceinline__ float ld(const unsigned short* p, size_t i) { return bf2f(p[i]); }
__device__ __forceinline__ float ld(const float* p, size_t i) { return p[i]; }
// 4-element loader (8B for bf16, 16B for fp32) — p must be 4-elem aligned
__device__ __forceinline__ void ld4(const unsigned short* p, float* out) {
  short4 v = *(const short4*)p;
  out[0] = bf2f((unsigned short)v.x); out[1] = bf2f((unsigned short)v.y);
  out[2] = bf2f((unsigned short)v.z); out[3] = bf2f((unsigned short)v.w);
}
__device__ __forceinline__ void ld4(const float* p, float* out) {
  float4 a = *(const float4*)p;
  out[0] = a.x; out[1] = a.y; out[2] = a.z; out[3] = a.w;
}

// ---------------- K0: adj -> bitmask bytes bm[i][j>>3]; dtype probe folded in.
__global__ __launch_bounds__(256) void k_bm(const void* adjv, const void* hv,
                                            int* __restrict__ flags,
                                            unsigned char* __restrict__ bm) {
  __shared__ int s_at;
  const int tid = threadIdx.x;
  if (tid == 0) s_at = 0;
  __syncthreads();
  const unsigned int* au = (const unsigned int*)adjv;
  unsigned int wv = au[tid];
  if ((wv & 0xFFFFu) == 0x3F80u) atomicOr(&s_at, 2);       // bf16 pair (1.0, x)
  else if (wv == 0x3F800000u) atomicOr(&s_at, 1);          // float32 1.0
  __syncthreads();
  const int at = (s_at & 2) ? 2 : (s_at & 1);
  const int i = blockIdx.x;
  if (i == 0 && tid < 64) {
    const unsigned short* hu = (const unsigned short*)hv;
    int bad = 0;
    for (int t = tid; t < 256; t += 64) {
      float v = bf2f(hu[t]);
      if (!(v > -1000.f && v < 1000.f)) bad = 1;           // fp32 halves look huge as bf16
    }
    unsigned long long m = __ballot(bad);
    if (tid == 0) { flags[0] = m ? 0 : 1; flags[1] = at; }
  }
#pragma unroll
  for (int rep = 0; rep < 2; rep++) {
    int jb = tid + rep * 256;
    unsigned int b = 0;
    if (at == 0) {
      const int4* arow = (const int4*)((const int*)adjv + (size_t)i * NN);
      int4 a0 = arow[jb * 2 + 0];
      int4 a1 = arow[jb * 2 + 1];
      b |= (a0.x > 0) ? 1u : 0u;  b |= (a0.y > 0) ? 2u : 0u;
      b |= (a0.z > 0) ? 4u : 0u;  b |= (a0.w > 0) ? 8u : 0u;
      b |= (a1.x > 0) ? 16u : 0u; b |= (a1.y > 0) ? 32u : 0u;
      b |= (a1.z > 0) ? 64u : 0u; b |= (a1.w > 0) ? 128u : 0u;
    } else if (at == 1) {
      const float* arow = (const float*)adjv + (size_t)i * NN + jb * 8;
      for (int t = 0; t < 8; t++) b |= (arow[t] > 0.5f) ? (1u << t) : 0u;
    } else {
      const unsigned short* arow = (const unsigned short*)adjv + (size_t)i * NN + jb * 8;
      for (int t = 0; t < 8; t++) b |= (bf2f(arow[t]) > 0.5f) ? (1u << t) : 0u;
    }
    bm[(size_t)i * 512 + jb] = (unsigned char)b;
  }
}

// ---------------- K1: wh = h@Wh + bWh. LDS-staged h tile (16x256), 16 waves =
// 4 heads x 4 k-quarters, two-slot LDS combine, pack phase writes int4 Bp1 units.
template <typename T>
__device__ __forceinline__ void wh_body(const T* h, const T* Wh, const T* bWh,
    const T* a_src, const T* a_dst, const T* a_b,
    unsigned short* __restrict__ Bp1, float* __restrict__ ssrc1, float* __restrict__ sdst1,
    float (*hs)[260], float (*wp)[16][260], float* av0, float* av1) {
  const int tid = threadIdx.x;
  const int w = tid >> 6, lane = tid & 63;
  const int head = w & 3, kq = w >> 2;
  const int rb = blockIdx.x;       // 0..255, 16 rows each
  const int R0 = rb * 16;
  const int d = lane;
  {
    const int r = tid >> 6, c4 = (tid & 63) * 4;
    float hv4[4];
    ld4(h + (size_t)(R0 + r) * 256 + c4, hv4);
    hs[r][c4 + 0] = hv4[0]; hs[r][c4 + 1] = hv4[1];
    hs[r][c4 + 2] = hv4[2]; hs[r][c4 + 3] = hv4[3];
  }
  if (tid < 256) av0[tid] = ld(a_src, tid);
  else if (tid < 512) av1[tid - 256] = ld(a_dst, tid - 256);
  __syncthreads();
  float acc[16];
  float bv = (kq == 0) ? ld(bWh, head * 64 + d) : 0.f;
#pragma unroll
  for (int r = 0; r < 16; r++) acc[r] = bv;
  const int k0 = kq * 64;
  for (int kb = 0; kb < 8; kb++) {
    float wv[8];
#pragma unroll
    for (int j = 0; j < 8; j++)
      wv[j] = ld(Wh, (size_t)(head * 256 + k0 + kb * 8 + j) * 64 + d);
#pragma unroll
    for (int r = 0; r < 16; r++) {
      float4 ha = *(const float4*)(&hs[r][k0 + kb * 8]);
      float4 hb = *(const float4*)(&hs[r][k0 + kb * 8 + 4]);
      acc[r] = fmaf(ha.x, wv[0], acc[r]);
      acc[r] = fmaf(ha.y, wv[1], acc[r]);
      acc[r] = fmaf(ha.z, wv[2], acc[r]);
      acc[r] = fmaf(ha.w, wv[3], acc[r]);
      acc[r] = fmaf(hb.x, wv[4], acc[r]);
      acc[r] = fmaf(hb.y, wv[5], acc[r]);
      acc[r] = fmaf(hb.z, wv[6], acc[r]);
      acc[r] = fmaf(hb.w, wv[7], acc[r]);
    }
  }
  if (kq >= 2) {
#pragma unroll
    for (int r = 0; r < 16; r++) wp[kq - 2][r][head * 64 + d] = acc[r];
  }
  __syncthreads();
  if (kq < 2) {
#pragma unroll
    for (int r = 0; r < 16; r++) wp[kq][r][head * 64 + d] += acc[r];
  }
  __syncthreads();
  if (tid < 512) {
    const int hh = tid >> 7, tt = (tid >> 5) & 3, lnh = tid & 31;
    const int q2 = (rb & 1) * 2 + (lnh >> 4);
    const int ln = q2 * 16 + (lnh & 15);
    const int dd = tt * 16 + (lnh & 15);
    const int rbase = (lnh >> 4) * 8;
    float v[8];
#pragma unroll
    for (int jj = 0; jj < 8; jj++)
      v[jj] = wp[0][rbase + jj][hh * 64 + dd] + wp[1][rbase + jj][hh * 64 + dd];
    i4s8 s;
    s.i.x = cvtpk(v[0], v[1]); s.i.y = cvtpk(v[2], v[3]);
    s.i.z = cvtpk(v[4], v[5]); s.i.w = cvtpk(v[6], v[7]);
    const int kb = rb >> 1;
    *(int4*)(Bp1 + ((((size_t)hh * 128 + kb) * 4 + tt) * 64 + ln) * 8) = s.i;
  } else if (tid < 576) {
    const int t2 = tid - 512;
    const int hh = t2 >> 4, r = t2 & 15;
    float ps = 0.f, pd = 0.f;
    for (int c = 0; c < 64; c++) {
      float wv2 = wp[0][r][hh * 64 + c] + wp[1][r][hh * 64 + c];
      ps = fmaf(wv2, av0[hh * 64 + c], ps);
      pd = fmaf(wv2, av1[hh * 64 + c], pd);
    }
    ssrc1[hh * NN + R0 + r] = ps + ld(a_b, hh);
    sdst1[hh * NN + R0 + r] = pd;
  }
}
__global__ __launch_bounds__(1024, 4) void k_wh(const void* h, const void* Wh, const void* bWh,
    const void* a_src, const void* a_dst, const void* a_b, const int* __restrict__ flags,
    unsigned short* Bp1, float* ssrc1, float* sdst1) {
  __shared__ float hs[16][260];
  __shared__ float wp[2][16][260];
  __shared__ float av0[256], av1[256];
  if (flags[0])
    wh_body<unsigned short>((const unsigned short*)h, (const unsigned short*)Wh,
        (const unsigned short*)bWh, (const unsigned short*)a_src,
        (const unsigned short*)a_dst, (const unsigned short*)a_b, Bp1, ssrc1, sdst1,
        hs, wp, av0, av1);
  else
    wh_body<float>((const float*)h, (const float*)Wh, (const float*)bWh, (const float*)a_src,
        (const float*)a_dst, (const float*)a_b, Bp1, ssrc1, sdst1, hs, wp, av0, av1);
}

// ---------------- K2: layer-1 attention. v2: grid 512 = 128 rowblocks(32 rows) x
// 4 kb-quarters -> 2 blocks/CU (32 waves/CU, was 16). launch_bounds(1024,8): VGPR
// cap 64 (measured 56 fits). Each wave (head, sl) handles 8 kb.
__global__ __launch_bounds__(1024, 8) void k_att1s(
    const unsigned char* __restrict__ bm, const float* __restrict__ ssrc,
    const float* __restrict__ sdst, const short8* __restrict__ Bp,
    float* __restrict__ part, float* __restrict__ partl) {
  const int rb = blockIdx.x & 127;
  const int qtr = blockIdx.x >> 7;   // 0..3
  const int tid = threadIdx.x;
  const int w = tid >> 6;
  const int head = w & 3;
  const int sl = w >> 2;  // 0..3: 8-kb slice within this quarter
  const int lane = tid & 63;
  const int r15 = lane & 15, quad = lane >> 4;
  const int row0 = rb * 32 + r15;
  const int row1 = row0 + 16;
  const float si0 = ssrc[head * NN + row0];
  const float si1 = ssrc[head * NN + row1];
  const unsigned char* bmr0 = bm + (size_t)row0 * 512;
  const unsigned char* bmr1 = bm + (size_t)row1 * 512;
  const float* sd = sdst + head * NN;
  const short8* Bh = Bp + (size_t)head * 128 * 4 * 64;
  f32x4 acc0[4], acc1[4];
#pragma unroll
  for (int t = 0; t < 4; t++) { acc0[t] = (f32x4){0,0,0,0}; acc1[t] = (f32x4){0,0,0,0}; }
  float ls0 = 0.f, ls1 = 0.f;
  const int kb0 = qtr * 32 + sl * 8;
  for (int g = 0; g < 2; g++) {          // 4 kb per group, bm fetched as int4
    const int kbg = kb0 + g * 4;
    int4 u0 = *(const int4*)(bmr0 + kbg * 4);
    int4 u1 = *(const int4*)(bmr1 + kbg * 4);
    int wd0[4] = {u0.x, u0.y, u0.z, u0.w};
    int wd1[4] = {u1.x, u1.y, u1.z, u1.w};
#pragma unroll
    for (int kk = 0; kk < 4; kk++) {
      const int kb = kbg + kk;
      const int j0 = kb * 32 + quad * 8;
      float4 q0 = *(const float4*)(sd + j0);
      float4 q1 = *(const float4*)(sd + j0 + 4);
      float sdv[8] = {q0.x, q0.y, q0.z, q0.w, q1.x, q1.y, q1.z, q1.w};
      unsigned int bits0 = (((unsigned int)wd0[kk]) >> (quad * 8)) & 0xffu;
      unsigned int bits1 = (((unsigned int)wd1[kk]) >> (quad * 8)) & 0xffu;
      float pe0[8], pe1[8];
#pragma unroll
      for (int jj = 0; jj < 8; jj++) {
        float t0 = si0 + sdv[jj];
        float e0 = __expf(fmaxf(t0, 0.2f * t0));
        pe0[jj] = ((bits0 >> jj) & 1u) ? e0 : 0.f;
        ls0 += pe0[jj];
        float t1 = si1 + sdv[jj];
        float e1 = __expf(fmaxf(t1, 0.2f * t1));
        pe1[jj] = ((bits1 >> jj) & 1u) ? e1 : 0.f;
        ls1 += pe1[jj];
      }
      i4s8 a0, a1;
      a0.i.x = cvtpk(pe0[0], pe0[1]); a0.i.y = cvtpk(pe0[2], pe0[3]);
      a0.i.z = cvtpk(pe0[4], pe0[5]); a0.i.w = cvtpk(pe0[6], pe0[7]);
      a1.i.x = cvtpk(pe1[0], pe1[1]); a1.i.y = cvtpk(pe1[2], pe1[3]);
      a1.i.z = cvtpk(pe1[4], pe1[5]); a1.i.w = cvtpk(pe1[6], pe1[7]);
      const short8* Bk = Bh + (size_t)kb * 256 + lane;
      short8 bt[4];
      bt[0] = Bk[0]; bt[1] = Bk[64]; bt[2] = Bk[128]; bt[3] = Bk[192];
#pragma unroll
      for (int t = 0; t < 4; t++) {
        acc0[t] = __builtin_amdgcn_mfma_f32_16x16x32_bf16(a0.s, bt[t], acc0[t], 0, 0, 0);
        acc1[t] = __builtin_amdgcn_mfma_f32_16x16x32_bf16(a1.s, bt[t], acc1[t], 0, 0, 0);
      }
    }
  }
  ls0 += __shfl_xor(ls0, 16); ls0 += __shfl_xor(ls0, 32);
  ls1 += __shfl_xor(ls1, 16); ls1 += __shfl_xor(ls1, 32);
  __shared__ float accs[8][16][66];
  __shared__ float lsh[8][16];
#define DOPASS(AC, LSV, PASS)                                                  \
  do {                                                                         \
    if (sl >= 2) {                                                             \
      const int slot = head * 2 + (sl - 2);                                    \
      if (lane < 16) lsh[slot][lane] = (LSV);                                  \
      _Pragma("unroll") for (int t = 0; t < 4; t++)                            \
        _Pragma("unroll") for (int gg = 0; gg < 4; gg++)                       \
          accs[slot][quad * 4 + gg][t * 16 + r15] = (AC)[t][gg];               \
    }                                                                          \
    __syncthreads();                                                           \
    if (sl < 2) {                                                              \
      const int slot = head * 2 + sl;                                          \
      if (lane < 16) lsh[slot][lane] += (LSV);                                 \
      _Pragma("unroll") for (int t = 0; t < 4; t++)                            \
        _Pragma("unroll") for (int gg = 0; gg < 4; gg++)                       \
          accs[slot][quad * 4 + gg][t * 16 + r15] += (AC)[t][gg];              \
    }                                                                          \
    __syncthreads();                                                           \
    _Pragma("unroll") for (int idx = tid; idx < 4096; idx += 1024) {           \
      int r = idx >> 8, hc = idx & 255;                                        \
      int hh = hc >> 6, col = hc & 63;                                         \
      part[((size_t)qtr * NN + rb * 32 + (PASS) * 16 + r) * 256 + hc] =        \
          accs[hh * 2][r][col] + accs[hh * 2 + 1][r][col];                     \
    }                                                                          \
    if (tid < 64)                                                              \
      partl[((size_t)qtr * 4 + (tid >> 4)) * NN + rb * 32 + (PASS) * 16 +      \
            (tid & 15)] = lsh[(tid >> 4) * 2][tid & 15] +                      \
                          lsh[(tid >> 4) * 2 + 1][tid & 15];                   \
    __syncthreads();                                                           \
  } while (0)
  DOPASS(acc0, ls0, 0);
  DOPASS(acc1, ls1, 1);
#undef DOPASS
}

// ---------------- K2-old (fallback if workspace too small for partials)
__global__ __launch_bounds__(1024) void k_att1(
    const unsigned char* __restrict__ bm, const float* __restrict__ ssrc,
    const float* __restrict__ sdst, const short8* __restrict__ Bp,
    unsigned short* __restrict__ x2) {
  const int rb = blockIdx.x;
  const int tid = threadIdx.x;
  const int w = tid >> 6;
  const int head = w & 3;
  const int slice = w >> 2;
  const int lane = tid & 63;
  const int r15 = lane & 15, quad = lane >> 4;
  const int row = rb * 16 + r15;
  const float si = ssrc[head * NN + row];
  const unsigned char* bmrow = bm + (size_t)row * 512;
  const float* sd = sdst + head * NN;
  const short8* Bh = Bp + (size_t)head * 128 * 4 * 64;
  f32x4 acc0 = {0, 0, 0, 0}, acc1 = {0, 0, 0, 0}, acc2 = {0, 0, 0, 0}, acc3 = {0, 0, 0, 0};
  float lsum = 0.f;
  const int kb0 = slice * 32;
  for (int kb = kb0; kb < kb0 + 32; kb++) {
    const int j0 = kb * 32 + quad * 8;
    unsigned int bits = bmrow[kb * 4 + quad];
    float4 q0 = *(const float4*)(sd + j0);
    float4 q1 = *(const float4*)(sd + j0 + 4);
    float sdv[8] = {q0.x, q0.y, q0.z, q0.w, q1.x, q1.y, q1.z, q1.w};
    short8 af;
#pragma unroll
    for (int jj = 0; jj < 8; jj++) {
      float t = si + sdv[jj];
      float lr = fmaxf(t, 0.2f * t);
      float e = __expf(lr);
      float pe = ((bits >> jj) & 1u) ? e : 0.0f;
      lsum += pe;
      af[jj] = (short)f2bf(pe);
    }
    const short8* Bk = Bh + (size_t)kb * 256 + lane;
    short8 b0 = Bk[0], b1 = Bk[64], b2 = Bk[128], b3 = Bk[192];
    acc0 = __builtin_amdgcn_mfma_f32_16x16x32_bf16(af, b0, acc0, 0, 0, 0);
    acc1 = __builtin_amdgcn_mfma_f32_16x16x32_bf16(af, b1, acc1, 0, 0, 0);
    acc2 = __builtin_amdgcn_mfma_f32_16x16x32_bf16(af, b2, acc2, 0, 0, 0);
    acc3 = __builtin_amdgcn_mfma_f32_16x16x32_bf16(af, b3, acc3, 0, 0, 0);
  }
  lsum += __shfl_xor(lsum, 16);
  lsum += __shfl_xor(lsum, 32);
  __shared__ float accs[8][16][66];
  __shared__ float ls[8][16];
  if (slice >= 2) {
    const int slot = w - 8;
    if (lane < 16) ls[slot][lane] = lsum;
#pragma unroll
    for (int g = 0; g < 4; g++) {
      int r = quad * 4 + g;
      accs[slot][r][ 0 + r15] = acc0[g];
      accs[slot][r][16 + r15] = acc1[g];
      accs[slot][r][32 + r15] = acc2[g];
      accs[slot][r][48 + r15] = acc3[g];
    }
  }
  __syncthreads();
  if (slice < 2) {
    const int slot = w;
    if (lane < 16) ls[slot][lane] += lsum;
#pragma unroll
    for (int g = 0; g < 4; g++) {
      int r = quad * 4 + g;
      accs[slot][r][ 0 + r15] += acc0[g];
      accs[slot][r][16 + r15] += acc1[g];
      accs[slot][r][32 + r15] += acc2[g];
      accs[slot][r][48 + r15] += acc3[g];
    }
  }
  __syncthreads();
#pragma unroll
  for (int c = tid; c < 4096; c += 1024) {
    int r = c >> 8, hc = c & 255;
    int hh = hc >> 6, col = hc & 63;
    float s = accs[hh][r][col] + accs[hh + 4][r][col];
    float lt = ls[hh][r] + ls[hh + 4][r];
    float v = (lt > 0.f) ? s / lt : 0.f;
    v = v > 0.f ? v : __expf(v) - 1.f;
    x2[(size_t)(rb * 16 + r) * 256 + hc] = f2bf(v);
  }
}

// ---------------- K3: wo = x2@Wo + bWo. Big path stages from 4-quarter part/partl
// (half-sum + normalize + elu inline); fallback path (part==nullptr) stages from x2.
template <typename T>
__device__ __forceinline__ void wo_body(const unsigned short* x2,
    const float* part, const float* partl,
    const T* Wo, const T* bWo, const T* ao_src, const T* ao_dst, const T* ao_b,
    unsigned short* __restrict__ Bp2, float* __restrict__ ssrc2, float* __restrict__ sdst2,
    float (*xs)[260], float (*wp)[16][68], float* av) {
  const int tid = threadIdx.x;
  const int w = tid >> 6, lane = tid & 63;
  const int rg = w & 3, kq = w >> 2;
  const int rb = blockIdx.x;         // 0..255, 16 rows each
  const int d = lane;
  {
    const int r = tid >> 6, c4 = (tid & 63) * 4;
    const int row = rb * 16 + r;
    if (part) {
      float4 p0 = *(const float4*)(part + ((size_t)0 * NN + row) * 256 + c4);
      float4 p1 = *(const float4*)(part + ((size_t)1 * NN + row) * 256 + c4);
      float4 p2 = *(const float4*)(part + ((size_t)2 * NN + row) * 256 + c4);
      float4 p3 = *(const float4*)(part + ((size_t)3 * NN + row) * 256 + c4);
      const int head = c4 >> 6;
      float lt = partl[((size_t)0 * 4 + head) * NN + row] +
                 partl[((size_t)1 * 4 + head) * NN + row] +
                 partl[((size_t)2 * 4 + head) * NN + row] +
                 partl[((size_t)3 * 4 + head) * NN + row];
      float rl = (lt > 0.f) ? 1.f / lt : 0.f;
      float v0 = (p0.x + p1.x + p2.x + p3.x) * rl;
      float v1 = (p0.y + p1.y + p2.y + p3.y) * rl;
      float v2 = (p0.z + p1.z + p2.z + p3.z) * rl;
      float v3 = (p0.w + p1.w + p2.w + p3.w) * rl;
      v0 = v0 > 0.f ? v0 : __expf(v0) - 1.f;
      v1 = v1 > 0.f ? v1 : __expf(v1) - 1.f;
      v2 = v2 > 0.f ? v2 : __expf(v2) - 1.f;
      v3 = v3 > 0.f ? v3 : __expf(v3) - 1.f;
      xs[r][c4 + 0] = v0; xs[r][c4 + 1] = v1;
      xs[r][c4 + 2] = v2; xs[r][c4 + 3] = v3;
    } else {
      float hv4[4];
      ld4(x2 + (size_t)row * 256 + c4, hv4);
      xs[r][c4 + 0] = hv4[0]; xs[r][c4 + 1] = hv4[1];
      xs[r][c4 + 2] = hv4[2]; xs[r][c4 + 3] = hv4[3];
    }
  }
  if (tid < 64) av[tid] = ld(ao_src, tid);
  else if (tid < 128) av[tid] = ld(ao_dst, tid - 64);
  __syncthreads();
  const int rr = rg * 4;
  float acc[4];
  float bv = (kq == 0) ? ld(bWo, d) : 0.f;
#pragma unroll
  for (int r = 0; r < 4; r++) acc[r] = bv;
  const int k0 = kq * 64;
  for (int kb = 0; kb < 8; kb++) {
    float wv[8];
#pragma unroll
    for (int j = 0; j < 8; j++)
      wv[j] = ld(Wo, (size_t)(k0 + kb * 8 + j) * 64 + d);
#pragma unroll
    for (int r = 0; r < 4; r++) {
      float4 ha = *(const float4*)(&xs[rr + r][k0 + kb * 8]);
      float4 hb = *(const float4*)(&xs[rr + r][k0 + kb * 8 + 4]);
      acc[r] = fmaf(ha.x, wv[0], acc[r]);
      acc[r] = fmaf(ha.y, wv[1], acc[r]);
      acc[r] = fmaf(ha.z, wv[2], acc[r]);
      acc[r] = fmaf(ha.w, wv[3], acc[r]);
      acc[r] = fmaf(hb.x, wv[4], acc[r]);
      acc[r] = fmaf(hb.y, wv[5], acc[r]);
      acc[r] = fmaf(hb.z, wv[6], acc[r]);
      acc[r] = fmaf(hb.w, wv[7], acc[r]);
    }
  }
  if (kq >= 2) {
#pragma unroll
    for (int r = 0; r < 4; r++) wp[kq - 2][rr + r][d] = acc[r];
  }
  __syncthreads();
  if (kq < 2) {
#pragma unroll
    for (int r = 0; r < 4; r++) wp[kq][rr + r][d] += acc[r];
  }
  __syncthreads();
  if (tid < 128) {
    const int tt = tid >> 5, lnh = tid & 31;
    const int q2 = (rb & 1) * 2 + (lnh >> 4);
    const int ln = q2 * 16 + (lnh & 15);
    const int dd = tt * 16 + (lnh & 15);
    const int rbase = (lnh >> 4) * 8;
    float v[8];
#pragma unroll
    for (int jj = 0; jj < 8; jj++)
      v[jj] = wp[0][rbase + jj][dd] + wp[1][rbase + jj][dd];
    i4s8 s;
    s.i.x = cvtpk(v[0], v[1]); s.i.y = cvtpk(v[2], v[3]);
    s.i.z = cvtpk(v[4], v[5]); s.i.w = cvtpk(v[6], v[7]);
    const int kb = rb >> 1;
    *(int4*)(Bp2 + (((size_t)kb * 4 + tt) * 64 + ln) * 8) = s.i;
  } else if (tid < 144) {
    const int r = tid - 128;
    float ps = 0.f, pd = 0.f;
    for (int c = 0; c < 64; c++) {
      float wv2 = wp[0][r][c] + wp[1][r][c];
      ps = fmaf(wv2, av[c], ps);
      pd = fmaf(wv2, av[64 + c], pd);
    }
    ssrc2[(size_t)rb * 16 + r] = ps + ld(ao_b, 0);
    sdst2[(size_t)rb * 16 + r] = pd;
  }
}
__global__ __launch_bounds__(1024, 4) void k_wo(const unsigned short* __restrict__ x2,
    const float* __restrict__ part, const float* __restrict__ partl,
    const void* Wo, const void* bWo, const void* ao_src, const void* ao_dst, const void* ao_b,
    const int* __restrict__ flags, unsigned short* Bp2, float* ssrc2, float* sdst2) {
  __shared__ float xs[16][260];
  __shared__ float wp[2][16][68];
  __shared__ float av[128];
  if (flags[0])
    wo_body<unsigned short>(x2, part, partl, (const unsigned short*)Wo,
        (const unsigned short*)bWo, (const unsigned short*)ao_src,
        (const unsigned short*)ao_dst, (const unsigned short*)ao_b,
        Bp2, ssrc2, sdst2, xs, wp, av);
  else
    wo_body<float>(x2, part, partl, (const float*)Wo, (const float*)bWo,
        (const float*)ao_src, (const float*)ao_dst, (const float*)ao_b,
        Bp2, ssrc2, sdst2, xs, wp, av);
}

// ---------------- K4-new: layer-2 attention split. Grid 512 = 256 rowblocks x
// 2 kb-halves -> 2 blocks/CU. Each wave 4 kb; writes fp32 partial + lsum.
__global__ __launch_bounds__(1024, 8) void k_att2s(
    const unsigned char* __restrict__ bm, const float* __restrict__ ssrc,
    const float* __restrict__ sdst, const short8* __restrict__ Bp,
    float* __restrict__ out2, float* __restrict__ l2p) {
  const int rb = blockIdx.x & 255;
  const int half = blockIdx.x >> 8;
  const int tid = threadIdx.x;
  const int w = tid >> 6;  // j-slice 0..15
  const int lane = tid & 63;
  const int r15 = lane & 15, quad = lane >> 4;
  const int row = rb * 16 + r15;
  const float si = ssrc[row];
  const unsigned char* bmrow = bm + (size_t)row * 512;
  f32x4 acc0 = {0, 0, 0, 0}, acc1 = {0, 0, 0, 0}, acc2 = {0, 0, 0, 0}, acc3 = {0, 0, 0, 0};
  float lsum = 0.f;
  const int kb0 = half * 64 + w * 4;
  {
    int4 ubm = *(const int4*)(bmrow + kb0 * 4);
    int wds[4] = {ubm.x, ubm.y, ubm.z, ubm.w};
#pragma unroll
    for (int kk = 0; kk < 4; kk++) {
      const int kb = kb0 + kk;
      const int j0 = kb * 32 + quad * 8;
      unsigned int bits = (((unsigned int)wds[kk]) >> (quad * 8)) & 0xffu;
      float4 q0 = *(const float4*)(sdst + j0);
      float4 q1 = *(const float4*)(sdst + j0 + 4);
      float sdv[8] = {q0.x, q0.y, q0.z, q0.w, q1.x, q1.y, q1.z, q1.w};
      float pe[8];
#pragma unroll
      for (int jj = 0; jj < 8; jj++) {
        float t = si + sdv[jj];
        float e = __expf(fmaxf(t, 0.2f * t));
        pe[jj] = ((bits >> jj) & 1u) ? e : 0.f;
        lsum += pe[jj];
      }
      i4s8 a;
      a.i.x = cvtpk(pe[0], pe[1]); a.i.y = cvtpk(pe[2], pe[3]);
      a.i.z = cvtpk(pe[4], pe[5]); a.i.w = cvtpk(pe[6], pe[7]);
      const short8* Bk = Bp + (size_t)kb * 256 + lane;
      short8 b0 = Bk[0], b1 = Bk[64], b2 = Bk[128], b3 = Bk[192];
      acc0 = __builtin_amdgcn_mfma_f32_16x16x32_bf16(a.s, b0, acc0, 0, 0, 0);
      acc1 = __builtin_amdgcn_mfma_f32_16x16x32_bf16(a.s, b1, acc1, 0, 0, 0);
      acc2 = __builtin_amdgcn_mfma_f32_16x16x32_bf16(a.s, b2, acc2, 0, 0, 0);
      acc3 = __builtin_amdgcn_mfma_f32_16x16x32_bf16(a.s, b3, acc3, 0, 0, 0);
    }
  }
  lsum += __shfl_xor(lsum, 16);
  lsum += __shfl_xor(lsum, 32);
  __shared__ float accs[8][16][66];
  __shared__ float ls2[8][16];
  if (w >= 8) {
    const int slot = w - 8;
    if (lane < 16) ls2[slot][lane] = lsum;
#pragma unroll
    for (int g = 0; g < 4; g++) {
      int r = quad * 4 + g;
      accs[slot][r][ 0 + r15] = acc0[g];
      accs[slot][r][16 + r15] = acc1[g];
      accs[slot][r][32 + r15] = acc2[g];
      accs[slot][r][48 + r15] = acc3[g];
    }
  }
  __syncthreads();
  if (w < 8) {
    const int slot = w;
    if (lane < 16) ls2[slot][lane] += lsum;
#pragma unroll
    for (int g = 0; g < 4; g++) {
      int r = quad * 4 + g;
      accs[slot][r][ 0 + r15] += acc0[g];
      accs[slot][r][16 + r15] += acc1[g];
      accs[slot][r][32 + r15] += acc2[g];
      accs[slot][r][48 + r15] += acc3[g];
    }
  }
  __syncthreads();
  {
    const int r = tid >> 6, col = tid & 63;
    float s = 0.f, lt = 0.f;
#pragma unroll
    for (int k = 0; k < 8; k++) { s += accs[k][r][col]; lt += ls2[k][r]; }
    out2[((size_t)half * NN + rb * 16 + r) * 64 + col] = s;
    if (col == 0) l2p[(size_t)half * NN + rb * 16 + r] = lt;
  }
}

// ---------------- K4-fin: sum 2 halves, normalize, elu, store.
__global__ __launch_bounds__(256) void k_att2f(const float* __restrict__ out2,
    const float* __restrict__ l2p, const int* __restrict__ flags,
    void* __restrict__ outv) {
  const int idx = blockIdx.x * 256 + threadIdx.x;  // 65536 = 4096 rows x 16 col-quads
  const int row = idx >> 4;
  const int c4 = (idx & 15) * 4;
  float4 a = *(const float4*)(out2 + (size_t)row * 64 + c4);
  float4 b = *(const float4*)(out2 + ((size_t)NN + row) * 64 + c4);
  float lt = l2p[row] + l2p[NN + row];
  float rl = (lt > 0.f) ? 1.f / lt : 0.f;
  float v0 = (a.x + b.x) * rl, v1 = (a.y + b.y) * rl;
  float v2 = (a.z + b.z) * rl, v3 = (a.w + b.w) * rl;
  v0 = v0 > 0.f ? v0 : __expf(v0) - 1.f;
  v1 = v1 > 0.f ? v1 : __expf(v1) - 1.f;
  v2 = v2 > 0.f ? v2 : __expf(v2) - 1.f;
  v3 = v3 > 0.f ? v3 : __expf(v3) - 1.f;
  size_t off = (size_t)row * 64 + c4;
  if (flags[0]) {
    uint2 st; st.x = cvtpk(v0, v1); st.y = cvtpk(v2, v3);
    *(uint2*)((unsigned short*)outv + off) = st;
  } else {
    float4 st; st.x = v0; st.y = v1; st.z = v2; st.w = v3;
    *(float4*)((float*)outv + off) = st;
  }
}

// ---------------- K4-old (fallback): monolithic layer-2 attention.
__global__ __launch_bounds__(1024) void k_att2(
    const unsigned char* __restrict__ bm, const float* __restrict__ ssrc,
    const float* __restrict__ sdst, const short8* __restrict__ Bp,
    const int* __restrict__ flags, void* __restrict__ outv) {
  const int rb = blockIdx.x;
  const int tid = threadIdx.x;
  const int w = tid >> 6;
  const int lane = tid & 63;
  const int r15 = lane & 15, quad = lane >> 4;
  const int row = rb * 16 + r15;
  const float si = ssrc[row];
  const unsigned char* bmrow = bm + (size_t)row * 512;
  f32x4 acc0 = {0, 0, 0, 0}, acc1 = {0, 0, 0, 0}, acc2 = {0, 0, 0, 0}, acc3 = {0, 0, 0, 0};
  float lsum = 0.f;
  const int kb0 = w * 8;
#pragma unroll
  for (int g = 0; g < 2; g++) {
    int4 ubm = *(const int4*)(bmrow + (kb0 + g * 4) * 4);
    int wds[4] = {ubm.x, ubm.y, ubm.z, ubm.w};
#pragma unroll
    for (int kk = 0; kk < 4; kk++) {
      const int kb = kb0 + g * 4 + kk;
      const int j0 = kb * 32 + quad * 8;
      unsigned int bits = (((unsigned int)wds[kk]) >> (quad * 8)) & 0xffu;
      float4 q0 = *(const float4*)(sdst + j0);
      float4 q1 = *(const float4*)(sdst + j0 + 4);
      float sdv[8] = {q0.x, q0.y, q0.z, q0.w, q1.x, q1.y, q1.z, q1.w};
      float pe[8];
#pragma unroll
      for (int jj = 0; jj < 8; jj++) {
        float t = si + sdv[jj];
        float e = __expf(fmaxf(t, 0.2f * t));
        pe[jj] = ((bits >> jj) & 1u) ? e : 0.f;
        lsum += pe[jj];
      }
      i4s8 a;
      a.i.x = cvtpk(pe[0], pe[1]); a.i.y = cvtpk(pe[2], pe[3]);
      a.i.z = cvtpk(pe[4], pe[5]); a.i.w = cvtpk(pe[6], pe[7]);
      const short8* Bk = Bp + (size_t)kb * 256 + lane;
      short8 b0 = Bk[0], b1 = Bk[64], b2 = Bk[128], b3 = Bk[192];
      acc0 = __builtin_amdgcn_mfma_f32_16x16x32_bf16(a.s, b0, acc0, 0, 0, 0);
      acc1 = __builtin_amdgcn_mfma_f32_16x16x32_bf16(a.s, b1, acc1, 0, 0, 0);
      acc2 = __builtin_amdgcn_mfma_f32_16x16x32_bf16(a.s, b2, acc2, 0, 0, 0);
      acc3 = __builtin_amdgcn_mfma_f32_16x16x32_bf16(a.s, b3, acc3, 0, 0, 0);
    }
  }
  lsum += __shfl_xor(lsum, 16);
  lsum += __shfl_xor(lsum, 32);
  __shared__ float accs[8][16][66];
  __shared__ float ls2[8][16];
  if (w >= 8) {
    const int slot = w - 8;
    if (lane < 16) ls2[slot][lane] = lsum;
#pragma unroll
    for (int g = 0; g < 4; g++) {
      int r = quad * 4 + g;
      accs[slot][r][ 0 + r15] = acc0[g];
      accs[slot][r][16 + r15] = acc1[g];
      accs[slot][r][32 + r15] = acc2[g];
      accs[slot][r][48 + r15] = acc3[g];
    }
  }
  __syncthreads();
  if (w < 8) {
    const int slot = w;
    if (lane < 16) ls2[slot][lane] += lsum;
#pragma unroll
    for (int g = 0; g < 4; g++) {
      int r = quad * 4 + g;
      accs[slot][r][ 0 + r15] += acc0[g];
      accs[slot][r][16 + r15] += acc1[g];
      accs[slot][r][32 + r15] += acc2[g];
      accs[slot][r][48 + r15] += acc3[g];
    }
  }
  __syncthreads();
  {
    const int r = tid >> 6, col = tid & 63;
    float s = 0.f, lt = 0.f;
#pragma unroll
    for (int k = 0; k < 8; k++) { s += accs[k][r][col]; lt += ls2[k][r]; }
    float v = (lt > 0.f) ? s / lt : 0.f;
    v = v > 0.f ? v : __expf(v) - 1.f;
    size_t idx = (size_t)(rb * 16 + r) * 64 + col;
    if (flags[0]) ((unsigned short*)outv)[idx] = f2bf(v);
    else          ((float*)outv)[idx] = v;
  }
}

extern "C" void kernel_launch(void* const* d_in, const int* in_sizes, int n_in,
                              void* d_out, int out_size, void* d_ws, size_t ws_size,
                              hipStream_t stream) {
  const void* h      = d_in[0];
  const void* adj    = d_in[1];
  const void* Wh     = d_in[2];
  const void* bWh    = d_in[3];
  const void* a_src  = d_in[4];
  const void* a_dst  = d_in[5];
  const void* a_b    = d_in[6];
  const void* Wo     = d_in[7];
  const void* bWo    = d_in[8];
  const void* ao_src = d_in[9];
  const void* ao_dst = d_in[10];
  const void* ao_b   = d_in[11];

  size_t need_old = 16 + (size_t)NN * 512 + (size_t)NHEADS * NN * HID * 2 +
                    (size_t)NN * 256 * 2 + (size_t)NN * 64 * 2 +
                    (size_t)NHEADS * NN * 8 + (size_t)NN * 8;
  size_t need_new = need_old + (size_t)4 * NN * 256 * 4 + (size_t)16 * NN * 4 +
                    (size_t)2 * NN * 64 * 4 + (size_t)2 * NN * 4;
  if (ws_size < need_old) {
    hipMemsetAsync(d_out, 0x45, (size_t)out_size * 2, stream);
    return;
  }
  const bool big = ws_size >= need_new;
  unsigned char* ws = (unsigned char*)d_ws;
  int* flags = (int*)ws;                        ws += 16;
  unsigned char* bmp = ws;                      ws += (size_t)NN * 512;               // 2 MB
  unsigned short* Bp1 = (unsigned short*)ws;    ws += (size_t)NHEADS * NN * HID * 2;  // 2 MB
  unsigned short* x2  = (unsigned short*)ws;    ws += (size_t)NN * 256 * 2;           // 2 MB
  unsigned short* Bp2 = (unsigned short*)ws;    ws += (size_t)NN * 64 * 2;            // 512 KB
  float* ssrc1 = (float*)ws;                    ws += (size_t)NHEADS * NN * 4;
  float* sdst1 = (float*)ws;                    ws += (size_t)NHEADS * NN * 4;
  float* ssrc2 = (float*)ws;                    ws += (size_t)NN * 4;
  float* sdst2 = (float*)ws;                    ws += (size_t)NN * 4;
  float* part  = (float*)ws;                    ws += (size_t)4 * NN * 256 * 4;       // 16 MB
  float* partl = (float*)ws;                    ws += (size_t)16 * NN * 4;            // 256 KB
  float* out2  = (float*)ws;                    ws += (size_t)2 * NN * 64 * 4;        // 2 MB
  float* l2p   = (float*)ws;                    ws += (size_t)2 * NN * 4;             // 32 KB

  k_bm   <<<dim3(4096), dim3(256),  0, stream>>>(adj, h, flags, bmp);
  k_wh   <<<dim3(256),  dim3(1024), 0, stream>>>(h, Wh, bWh, a_src, a_dst, a_b, flags,
                                                 Bp1, ssrc1, sdst1);
  if (big) {
    k_att1s<<<dim3(512), dim3(1024), 0, stream>>>(bmp, ssrc1, sdst1, (const short8*)Bp1,
                                                  part, partl);
    k_wo   <<<dim3(256), dim3(1024), 0, stream>>>(x2, part, partl, Wo, bWo, ao_src, ao_dst,
                                                  ao_b, flags, Bp2, ssrc2, sdst2);
    k_att2s<<<dim3(512), dim3(1024), 0, stream>>>(bmp, ssrc2, sdst2, (const short8*)Bp2,
                                                  out2, l2p);
    k_att2f<<<dim3(256), dim3(256),  0, stream>>>(out2, l2p, flags, d_out);
  } else {
    k_att1 <<<dim3(256), dim3(1024), 0, stream>>>(bmp, ssrc1, sdst1, (const short8*)Bp1, x2);
    k_wo   <<<dim3(256), dim3(1024), 0, stream>>>(x2, (const float*)nullptr,
                                                  (const float*)nullptr, Wo, bWo, ao_src,
                                                  ao_dst, ao_b, flags, Bp2, ssrc2, sdst2);
    k_att2 <<<dim3(256), dim3(1024), 0, stream>>>(bmp, ssrc2, sdst2, (const short8*)Bp2,
                                                  flags, d_out);
  }
}

// Round 10
// 186.576 us; speedup vs baseline: 1.8208x; 1.8208x over previous
//
#include <hip/hip_runtime.h>

#define NN 4096
#define NHEADS 4
#define HID 64
#define INDIM 256

using short8 = __attribute__((ext_vector_type(8))) short;
using f32x4  = __attribute__((ext_vector_type(4))) float;

union f32u { float f; unsigned int u; };
union i4s8 { int4 i; short8 s; };

__device__ __forceinline__ float bf2f(unsigned short s) {
  f32u x; x.u = ((unsigned int)s) << 16; return x.f;
}
__device__ __forceinline__ unsigned short f2bf(float f) {
  f32u x; x.f = f;
  unsigned int r = x.u + 0x7fffu + ((x.u >> 16) & 1u);
  return (unsigned short)(r >> 16);
}
// packed f32x2 -> bf16x2 (RNE, same as f2bf) in one instruction
__device__ __forceinline__ unsigned int cvtpk(float lo, float hi) {
  unsigned int r;
  asm("v_cvt_pk_bf16_f32 %0, %1, %2" : "=v"(r) : "v"(lo), "v"(hi));
  return r;
}

// overloaded external-input loaders
__device__ __forceinline__ float ld(const unsigned short* p, size_t i) { return bf2f(p[i]); }
__device__ __forceinline__ float ld(const float* p, size_t i) { return p[i]; }
// 4-element loader (8B for bf16, 16B for fp32) — p must be 4-elem aligned
__device__ __forceinline__ void ld4(const unsigned short* p, float* out) {
  short4 v = *(const short4*)p;
  out[0] = bf2f((unsigned short)v.x); out[1] = bf2f((unsigned short)v.y);
  out[2] = bf2f((unsigned short)v.z); out[3] = bf2f((unsigned short)v.w);
}
__device__ __forceinline__ void ld4(const float* p, float* out) {
  float4 a = *(const float4*)p;
  out[0] = a.x; out[1] = a.y; out[2] = a.z; out[3] = a.w;
}

// ---------------- K0: adj -> bitmask bytes bm[i][j>>3]; dtype probe folded in.
__global__ __launch_bounds__(256) void k_bm(const void* adjv, const void* hv,
                                            int* __restrict__ flags,
                                            unsigned char* __restrict__ bm) {
  __shared__ int s_at;
  const int tid = threadIdx.x;
  if (tid == 0) s_at = 0;
  __syncthreads();
  const unsigned int* au = (const unsigned int*)adjv;
  unsigned int wv = au[tid];
  if ((wv & 0xFFFFu) == 0x3F80u) atomicOr(&s_at, 2);       // bf16 pair (1.0, x)
  else if (wv == 0x3F800000u) atomicOr(&s_at, 1);          // float32 1.0
  __syncthreads();
  const int at = (s_at & 2) ? 2 : (s_at & 1);
  const int i = blockIdx.x;
  if (i == 0 && tid < 64) {
    const unsigned short* hu = (const unsigned short*)hv;
    int bad = 0;
    for (int t = tid; t < 256; t += 64) {
      float v = bf2f(hu[t]);
      if (!(v > -1000.f && v < 1000.f)) bad = 1;           // fp32 halves look huge as bf16
    }
    unsigned long long m = __ballot(bad);
    if (tid == 0) { flags[0] = m ? 0 : 1; flags[1] = at; }
  }
#pragma unroll
  for (int rep = 0; rep < 2; rep++) {
    int jb = tid + rep * 256;
    unsigned int b = 0;
    if (at == 0) {
      const int4* arow = (const int4*)((const int*)adjv + (size_t)i * NN);
      int4 a0 = arow[jb * 2 + 0];
      int4 a1 = arow[jb * 2 + 1];
      b |= (a0.x > 0) ? 1u : 0u;  b |= (a0.y > 0) ? 2u : 0u;
      b |= (a0.z > 0) ? 4u : 0u;  b |= (a0.w > 0) ? 8u : 0u;
      b |= (a1.x > 0) ? 16u : 0u; b |= (a1.y > 0) ? 32u : 0u;
      b |= (a1.z > 0) ? 64u : 0u; b |= (a1.w > 0) ? 128u : 0u;
    } else if (at == 1) {
      const float* arow = (const float*)adjv + (size_t)i * NN + jb * 8;
      for (int t = 0; t < 8; t++) b |= (arow[t] > 0.5f) ? (1u << t) : 0u;
    } else {
      const unsigned short* arow = (const unsigned short*)adjv + (size_t)i * NN + jb * 8;
      for (int t = 0; t < 8; t++) b |= (bf2f(arow[t]) > 0.5f) ? (1u << t) : 0u;
    }
    bm[(size_t)i * 512 + jb] = (unsigned char)b;
  }
}

// ---------------- K1: wh = h@Wh + bWh. LDS-staged h tile (16x256), 16 waves =
// 4 heads x 4 k-quarters, two-slot LDS combine, pack phase writes int4 Bp1 units.
template <typename T>
__device__ __forceinline__ void wh_body(const T* h, const T* Wh, const T* bWh,
    const T* a_src, const T* a_dst, const T* a_b,
    unsigned short* __restrict__ Bp1, float* __restrict__ ssrc1, float* __restrict__ sdst1,
    float (*hs)[260], float (*wp)[16][260], float* av0, float* av1) {
  const int tid = threadIdx.x;
  const int w = tid >> 6, lane = tid & 63;
  const int head = w & 3, kq = w >> 2;
  const int rb = blockIdx.x;       // 0..255, 16 rows each
  const int R0 = rb * 16;
  const int d = lane;
  {
    const int r = tid >> 6, c4 = (tid & 63) * 4;
    float hv4[4];
    ld4(h + (size_t)(R0 + r) * 256 + c4, hv4);
    hs[r][c4 + 0] = hv4[0]; hs[r][c4 + 1] = hv4[1];
    hs[r][c4 + 2] = hv4[2]; hs[r][c4 + 3] = hv4[3];
  }
  if (tid < 256) av0[tid] = ld(a_src, tid);
  else if (tid < 512) av1[tid - 256] = ld(a_dst, tid - 256);
  __syncthreads();
  float acc[16];
  float bv = (kq == 0) ? ld(bWh, head * 64 + d) : 0.f;
#pragma unroll
  for (int r = 0; r < 16; r++) acc[r] = bv;
  const int k0 = kq * 64;
  for (int kb = 0; kb < 8; kb++) {
    float wv[8];
#pragma unroll
    for (int j = 0; j < 8; j++)
      wv[j] = ld(Wh, (size_t)(head * 256 + k0 + kb * 8 + j) * 64 + d);
#pragma unroll
    for (int r = 0; r < 16; r++) {
      float4 ha = *(const float4*)(&hs[r][k0 + kb * 8]);
      float4 hb = *(const float4*)(&hs[r][k0 + kb * 8 + 4]);
      acc[r] = fmaf(ha.x, wv[0], acc[r]);
      acc[r] = fmaf(ha.y, wv[1], acc[r]);
      acc[r] = fmaf(ha.z, wv[2], acc[r]);
      acc[r] = fmaf(ha.w, wv[3], acc[r]);
      acc[r] = fmaf(hb.x, wv[4], acc[r]);
      acc[r] = fmaf(hb.y, wv[5], acc[r]);
      acc[r] = fmaf(hb.z, wv[6], acc[r]);
      acc[r] = fmaf(hb.w, wv[7], acc[r]);
    }
  }
  if (kq >= 2) {
#pragma unroll
    for (int r = 0; r < 16; r++) wp[kq - 2][r][head * 64 + d] = acc[r];
  }
  __syncthreads();
  if (kq < 2) {
#pragma unroll
    for (int r = 0; r < 16; r++) wp[kq][r][head * 64 + d] += acc[r];
  }
  __syncthreads();
  if (tid < 512) {
    const int hh = tid >> 7, tt = (tid >> 5) & 3, lnh = tid & 31;
    const int q2 = (rb & 1) * 2 + (lnh >> 4);
    const int ln = q2 * 16 + (lnh & 15);
    const int dd = tt * 16 + (lnh & 15);
    const int rbase = (lnh >> 4) * 8;
    float v[8];
#pragma unroll
    for (int jj = 0; jj < 8; jj++)
      v[jj] = wp[0][rbase + jj][hh * 64 + dd] + wp[1][rbase + jj][hh * 64 + dd];
    i4s8 s;
    s.i.x = cvtpk(v[0], v[1]); s.i.y = cvtpk(v[2], v[3]);
    s.i.z = cvtpk(v[4], v[5]); s.i.w = cvtpk(v[6], v[7]);
    const int kb = rb >> 1;
    *(int4*)(Bp1 + ((((size_t)hh * 128 + kb) * 4 + tt) * 64 + ln) * 8) = s.i;
  } else if (tid < 576) {
    const int t2 = tid - 512;
    const int hh = t2 >> 4, r = t2 & 15;
    float ps = 0.f, pd = 0.f;
    for (int c = 0; c < 64; c++) {
      float wv2 = wp[0][r][hh * 64 + c] + wp[1][r][hh * 64 + c];
      ps = fmaf(wv2, av0[hh * 64 + c], ps);
      pd = fmaf(wv2, av1[hh * 64 + c], pd);
    }
    ssrc1[hh * NN + R0 + r] = ps + ld(a_b, hh);
    sdst1[hh * NN + R0 + r] = pd;
  }
}
__global__ __launch_bounds__(1024, 4) void k_wh(const void* h, const void* Wh, const void* bWh,
    const void* a_src, const void* a_dst, const void* a_b, const int* __restrict__ flags,
    unsigned short* Bp1, float* ssrc1, float* sdst1) {
  __shared__ float hs[16][260];
  __shared__ float wp[2][16][260];
  __shared__ float av0[256], av1[256];
  if (flags[0])
    wh_body<unsigned short>((const unsigned short*)h, (const unsigned short*)Wh,
        (const unsigned short*)bWh, (const unsigned short*)a_src,
        (const unsigned short*)a_dst, (const unsigned short*)a_b, Bp1, ssrc1, sdst1,
        hs, wp, av0, av1);
  else
    wh_body<float>((const float*)h, (const float*)Wh, (const float*)bWh, (const float*)a_src,
        (const float*)a_dst, (const float*)a_b, Bp1, ssrc1, sdst1, hs, wp, av0, av1);
}

// ---------------- K2: layer-1 attention. Grid 512 = 128 rowblocks(32 rows) x
// 4 kb-quarters. launch_bounds(1024,4): VGPR cap 128 -> compiler lands ~56
// naturally (round-8 measured), which is <=64, so HW co-schedules 2 blocks/CU
// (32 waves) on its own. DO NOT force (1024,8): the hard cap 64 made the
// compiler spill to scratch (round-9: VGPR 32, WRITE_SIZE 552 MB, 180 us).
__global__ __launch_bounds__(1024, 4) void k_att1s(
    const unsigned char* __restrict__ bm, const float* __restrict__ ssrc,
    const float* __restrict__ sdst, const short8* __restrict__ Bp,
    float* __restrict__ part, float* __restrict__ partl) {
  const int rb = blockIdx.x & 127;
  const int qtr = blockIdx.x >> 7;   // 0..3
  const int tid = threadIdx.x;
  const int w = tid >> 6;
  const int head = w & 3;
  const int sl = w >> 2;  // 0..3: 8-kb slice within this quarter
  const int lane = tid & 63;
  const int r15 = lane & 15, quad = lane >> 4;
  const int row0 = rb * 32 + r15;
  const int row1 = row0 + 16;
  const float si0 = ssrc[head * NN + row0];
  const float si1 = ssrc[head * NN + row1];
  const unsigned char* bmr0 = bm + (size_t)row0 * 512;
  const unsigned char* bmr1 = bm + (size_t)row1 * 512;
  const float* sd = sdst + head * NN;
  const short8* Bh = Bp + (size_t)head * 128 * 4 * 64;
  f32x4 acc0[4], acc1[4];
#pragma unroll
  for (int t = 0; t < 4; t++) { acc0[t] = (f32x4){0,0,0,0}; acc1[t] = (f32x4){0,0,0,0}; }
  float ls0 = 0.f, ls1 = 0.f;
  const int kb0 = qtr * 32 + sl * 8;
  for (int g = 0; g < 2; g++) {          // 4 kb per group, bm fetched as int4
    const int kbg = kb0 + g * 4;
    int4 u0 = *(const int4*)(bmr0 + kbg * 4);
    int4 u1 = *(const int4*)(bmr1 + kbg * 4);
    int wd0[4] = {u0.x, u0.y, u0.z, u0.w};
    int wd1[4] = {u1.x, u1.y, u1.z, u1.w};
#pragma unroll
    for (int kk = 0; kk < 4; kk++) {
      const int kb = kbg + kk;
      const int j0 = kb * 32 + quad * 8;
      float4 q0 = *(const float4*)(sd + j0);
      float4 q1 = *(const float4*)(sd + j0 + 4);
      float sdv[8] = {q0.x, q0.y, q0.z, q0.w, q1.x, q1.y, q1.z, q1.w};
      unsigned int bits0 = (((unsigned int)wd0[kk]) >> (quad * 8)) & 0xffu;
      unsigned int bits1 = (((unsigned int)wd1[kk]) >> (quad * 8)) & 0xffu;
      float pe0[8], pe1[8];
#pragma unroll
      for (int jj = 0; jj < 8; jj++) {
        float t0 = si0 + sdv[jj];
        float e0 = __expf(fmaxf(t0, 0.2f * t0));
        pe0[jj] = ((bits0 >> jj) & 1u) ? e0 : 0.f;
        ls0 += pe0[jj];
        float t1 = si1 + sdv[jj];
        float e1 = __expf(fmaxf(t1, 0.2f * t1));
        pe1[jj] = ((bits1 >> jj) & 1u) ? e1 : 0.f;
        ls1 += pe1[jj];
      }
      i4s8 a0, a1;
      a0.i.x = cvtpk(pe0[0], pe0[1]); a0.i.y = cvtpk(pe0[2], pe0[3]);
      a0.i.z = cvtpk(pe0[4], pe0[5]); a0.i.w = cvtpk(pe0[6], pe0[7]);
      a1.i.x = cvtpk(pe1[0], pe1[1]); a1.i.y = cvtpk(pe1[2], pe1[3]);
      a1.i.z = cvtpk(pe1[4], pe1[5]); a1.i.w = cvtpk(pe1[6], pe1[7]);
      const short8* Bk = Bh + (size_t)kb * 256 + lane;
      short8 bt[4];
      bt[0] = Bk[0]; bt[1] = Bk[64]; bt[2] = Bk[128]; bt[3] = Bk[192];
#pragma unroll
      for (int t = 0; t < 4; t++) {
        acc0[t] = __builtin_amdgcn_mfma_f32_16x16x32_bf16(a0.s, bt[t], acc0[t], 0, 0, 0);
        acc1[t] = __builtin_amdgcn_mfma_f32_16x16x32_bf16(a1.s, bt[t], acc1[t], 0, 0, 0);
      }
    }
  }
  ls0 += __shfl_xor(ls0, 16); ls0 += __shfl_xor(ls0, 32);
  ls1 += __shfl_xor(ls1, 16); ls1 += __shfl_xor(ls1, 32);
  __shared__ float accs[8][16][66];
  __shared__ float lsh[8][16];
#define DOPASS(AC, LSV, PASS)                                                  \
  do {                                                                         \
    if (sl >= 2) {                                                             \
      const int slot = head * 2 + (sl - 2);                                    \
      if (lane < 16) lsh[slot][lane] = (LSV);                                  \
      _Pragma("unroll") for (int t = 0; t < 4; t++)                            \
        _Pragma("unroll") for (int gg = 0; gg < 4; gg++)                       \
          accs[slot][quad * 4 + gg][t * 16 + r15] = (AC)[t][gg];               \
    }                                                                          \
    __syncthreads();                                                           \
    if (sl < 2) {                                                              \
      const int slot = head * 2 + sl;                                          \
      if (lane < 16) lsh[slot][lane] += (LSV);                                 \
      _Pragma("unroll") for (int t = 0; t < 4; t++)                            \
        _Pragma("unroll") for (int gg = 0; gg < 4; gg++)                       \
          accs[slot][quad * 4 + gg][t * 16 + r15] += (AC)[t][gg];              \
    }                                                                          \
    __syncthreads();                                                           \
    _Pragma("unroll") for (int idx = tid; idx < 4096; idx += 1024) {           \
      int r = idx >> 8, hc = idx & 255;                                        \
      int hh = hc >> 6, col = hc & 63;                                         \
      part[((size_t)qtr * NN + rb * 32 + (PASS) * 16 + r) * 256 + hc] =        \
          accs[hh * 2][r][col] + accs[hh * 2 + 1][r][col];                     \
    }                                                                          \
    if (tid < 64)                                                              \
      partl[((size_t)qtr * 4 + (tid >> 4)) * NN + rb * 32 + (PASS) * 16 +      \
            (tid & 15)] = lsh[(tid >> 4) * 2][tid & 15] +                      \
                          lsh[(tid >> 4) * 2 + 1][tid & 15];                   \
    __syncthreads();                                                           \
  } while (0)
  DOPASS(acc0, ls0, 0);
  DOPASS(acc1, ls1, 1);
#undef DOPASS
}

// ---------------- K2-old (fallback if workspace too small for partials)
__global__ __launch_bounds__(1024) void k_att1(
    const unsigned char* __restrict__ bm, const float* __restrict__ ssrc,
    const float* __restrict__ sdst, const short8* __restrict__ Bp,
    unsigned short* __restrict__ x2) {
  const int rb = blockIdx.x;
  const int tid = threadIdx.x;
  const int w = tid >> 6;
  const int head = w & 3;
  const int slice = w >> 2;
  const int lane = tid & 63;
  const int r15 = lane & 15, quad = lane >> 4;
  const int row = rb * 16 + r15;
  const float si = ssrc[head * NN + row];
  const unsigned char* bmrow = bm + (size_t)row * 512;
  const float* sd = sdst + head * NN;
  const short8* Bh = Bp + (size_t)head * 128 * 4 * 64;
  f32x4 acc0 = {0, 0, 0, 0}, acc1 = {0, 0, 0, 0}, acc2 = {0, 0, 0, 0}, acc3 = {0, 0, 0, 0};
  float lsum = 0.f;
  const int kb0 = slice * 32;
  for (int kb = kb0; kb < kb0 + 32; kb++) {
    const int j0 = kb * 32 + quad * 8;
    unsigned int bits = bmrow[kb * 4 + quad];
    float4 q0 = *(const float4*)(sd + j0);
    float4 q1 = *(const float4*)(sd + j0 + 4);
    float sdv[8] = {q0.x, q0.y, q0.z, q0.w, q1.x, q1.y, q1.z, q1.w};
    short8 af;
#pragma unroll
    for (int jj = 0; jj < 8; jj++) {
      float t = si + sdv[jj];
      float lr = fmaxf(t, 0.2f * t);
      float e = __expf(lr);
      float pe = ((bits >> jj) & 1u) ? e : 0.0f;
      lsum += pe;
      af[jj] = (short)f2bf(pe);
    }
    const short8* Bk = Bh + (size_t)kb * 256 + lane;
    short8 b0 = Bk[0], b1 = Bk[64], b2 = Bk[128], b3 = Bk[192];
    acc0 = __builtin_amdgcn_mfma_f32_16x16x32_bf16(af, b0, acc0, 0, 0, 0);
    acc1 = __builtin_amdgcn_mfma_f32_16x16x32_bf16(af, b1, acc1, 0, 0, 0);
    acc2 = __builtin_amdgcn_mfma_f32_16x16x32_bf16(af, b2, acc2, 0, 0, 0);
    acc3 = __builtin_amdgcn_mfma_f32_16x16x32_bf16(af, b3, acc3, 0, 0, 0);
  }
  lsum += __shfl_xor(lsum, 16);
  lsum += __shfl_xor(lsum, 32);
  __shared__ float accs[8][16][66];
  __shared__ float ls[8][16];
  if (slice >= 2) {
    const int slot = w - 8;
    if (lane < 16) ls[slot][lane] = lsum;
#pragma unroll
    for (int g = 0; g < 4; g++) {
      int r = quad * 4 + g;
      accs[slot][r][ 0 + r15] = acc0[g];
      accs[slot][r][16 + r15] = acc1[g];
      accs[slot][r][32 + r15] = acc2[g];
      accs[slot][r][48 + r15] = acc3[g];
    }
  }
  __syncthreads();
  if (slice < 2) {
    const int slot = w;
    if (lane < 16) ls[slot][lane] += lsum;
#pragma unroll
    for (int g = 0; g < 4; g++) {
      int r = quad * 4 + g;
      accs[slot][r][ 0 + r15] += acc0[g];
      accs[slot][r][16 + r15] += acc1[g];
      accs[slot][r][32 + r15] += acc2[g];
      accs[slot][r][48 + r15] += acc3[g];
    }
  }
  __syncthreads();
#pragma unroll
  for (int c = tid; c < 4096; c += 1024) {
    int r = c >> 8, hc = c & 255;
    int hh = hc >> 6, col = hc & 63;
    float s = accs[hh][r][col] + accs[hh + 4][r][col];
    float lt = ls[hh][r] + ls[hh + 4][r];
    float v = (lt > 0.f) ? s / lt : 0.f;
    v = v > 0.f ? v : __expf(v) - 1.f;
    x2[(size_t)(rb * 16 + r) * 256 + hc] = f2bf(v);
  }
}

// ---------------- K3: wo = x2@Wo + bWo. Big path stages from 4-quarter part/partl
// (sum + normalize + elu inline); fallback path (part==nullptr) stages from x2.
template <typename T>
__device__ __forceinline__ void wo_body(const unsigned short* x2,
    const float* part, const float* partl,
    const T* Wo, const T* bWo, const T* ao_src, const T* ao_dst, const T* ao_b,
    unsigned short* __restrict__ Bp2, float* __restrict__ ssrc2, float* __restrict__ sdst2,
    float (*xs)[260], float (*wp)[16][68], float* av) {
  const int tid = threadIdx.x;
  const int w = tid >> 6, lane = tid & 63;
  const int rg = w & 3, kq = w >> 2;
  const int rb = blockIdx.x;         // 0..255, 16 rows each
  const int d = lane;
  {
    const int r = tid >> 6, c4 = (tid & 63) * 4;
    const int row = rb * 16 + r;
    if (part) {
      float4 p0 = *(const float4*)(part + ((size_t)0 * NN + row) * 256 + c4);
      float4 p1 = *(const float4*)(part + ((size_t)1 * NN + row) * 256 + c4);
      float4 p2 = *(const float4*)(part + ((size_t)2 * NN + row) * 256 + c4);
      float4 p3 = *(const float4*)(part + ((size_t)3 * NN + row) * 256 + c4);
      const int head = c4 >> 6;
      float lt = partl[((size_t)0 * 4 + head) * NN + row] +
                 partl[((size_t)1 * 4 + head) * NN + row] +
                 partl[((size_t)2 * 4 + head) * NN + row] +
                 partl[((size_t)3 * 4 + head) * NN + row];
      float rl = (lt > 0.f) ? 1.f / lt : 0.f;
      float v0 = (p0.x + p1.x + p2.x + p3.x) * rl;
      float v1 = (p0.y + p1.y + p2.y + p3.y) * rl;
      float v2 = (p0.z + p1.z + p2.z + p3.z) * rl;
      float v3 = (p0.w + p1.w + p2.w + p3.w) * rl;
      v0 = v0 > 0.f ? v0 : __expf(v0) - 1.f;
      v1 = v1 > 0.f ? v1 : __expf(v1) - 1.f;
      v2 = v2 > 0.f ? v2 : __expf(v2) - 1.f;
      v3 = v3 > 0.f ? v3 : __expf(v3) - 1.f;
      xs[r][c4 + 0] = v0; xs[r][c4 + 1] = v1;
      xs[r][c4 + 2] = v2; xs[r][c4 + 3] = v3;
    } else {
      float hv4[4];
      ld4(x2 + (size_t)row * 256 + c4, hv4);
      xs[r][c4 + 0] = hv4[0]; xs[r][c4 + 1] = hv4[1];
      xs[r][c4 + 2] = hv4[2]; xs[r][c4 + 3] = hv4[3];
    }
  }
  if (tid < 64) av[tid] = ld(ao_src, tid);
  else if (tid < 128) av[tid] = ld(ao_dst, tid - 64);
  __syncthreads();
  const int rr = rg * 4;
  float acc[4];
  float bv = (kq == 0) ? ld(bWo, d) : 0.f;
#pragma unroll
  for (int r = 0; r < 4; r++) acc[r] = bv;
  const int k0 = kq * 64;
  for (int kb = 0; kb < 8; kb++) {
    float wv[8];
#pragma unroll
    for (int j = 0; j < 8; j++)
      wv[j] = ld(Wo, (size_t)(k0 + kb * 8 + j) * 64 + d);
#pragma unroll
    for (int r = 0; r < 4; r++) {
      float4 ha = *(const float4*)(&xs[rr + r][k0 + kb * 8]);
      float4 hb = *(const float4*)(&xs[rr + r][k0 + kb * 8 + 4]);
      acc[r] = fmaf(ha.x, wv[0], acc[r]);
      acc[r] = fmaf(ha.y, wv[1], acc[r]);
      acc[r] = fmaf(ha.z, wv[2], acc[r]);
      acc[r] = fmaf(ha.w, wv[3], acc[r]);
      acc[r] = fmaf(hb.x, wv[4], acc[r]);
      acc[r] = fmaf(hb.y, wv[5], acc[r]);
      acc[r] = fmaf(hb.z, wv[6], acc[r]);
      acc[r] = fmaf(hb.w, wv[7], acc[r]);
    }
  }
  if (kq >= 2) {
#pragma unroll
    for (int r = 0; r < 4; r++) wp[kq - 2][rr + r][d] = acc[r];
  }
  __syncthreads();
  if (kq < 2) {
#pragma unroll
    for (int r = 0; r < 4; r++) wp[kq][rr + r][d] += acc[r];
  }
  __syncthreads();
  if (tid < 128) {
    const int tt = tid >> 5, lnh = tid & 31;
    const int q2 = (rb & 1) * 2 + (lnh >> 4);
    const int ln = q2 * 16 + (lnh & 15);
    const int dd = tt * 16 + (lnh & 15);
    const int rbase = (lnh >> 4) * 8;
    float v[8];
#pragma unroll
    for (int jj = 0; jj < 8; jj++)
      v[jj] = wp[0][rbase + jj][dd] + wp[1][rbase + jj][dd];
    i4s8 s;
    s.i.x = cvtpk(v[0], v[1]); s.i.y = cvtpk(v[2], v[3]);
    s.i.z = cvtpk(v[4], v[5]); s.i.w = cvtpk(v[6], v[7]);
    const int kb = rb >> 1;
    *(int4*)(Bp2 + (((size_t)kb * 4 + tt) * 64 + ln) * 8) = s.i;
  } else if (tid < 144) {
    const int r = tid - 128;
    float ps = 0.f, pd = 0.f;
    for (int c = 0; c < 64; c++) {
      float wv2 = wp[0][r][c] + wp[1][r][c];
      ps = fmaf(wv2, av[c], ps);
      pd = fmaf(wv2, av[64 + c], pd);
    }
    ssrc2[(size_t)rb * 16 + r] = ps + ld(ao_b, 0);
    sdst2[(size_t)rb * 16 + r] = pd;
  }
}
__global__ __launch_bounds__(1024, 4) void k_wo(const unsigned short* __restrict__ x2,
    const float* __restrict__ part, const float* __restrict__ partl,
    const void* Wo, const void* bWo, const void* ao_src, const void* ao_dst, const void* ao_b,
    const int* __restrict__ flags, unsigned short* Bp2, float* ssrc2, float* sdst2) {
  __shared__ float xs[16][260];
  __shared__ float wp[2][16][68];
  __shared__ float av[128];
  if (flags[0])
    wo_body<unsigned short>(x2, part, partl, (const unsigned short*)Wo,
        (const unsigned short*)bWo, (const unsigned short*)ao_src,
        (const unsigned short*)ao_dst, (const unsigned short*)ao_b,
        Bp2, ssrc2, sdst2, xs, wp, av);
  else
    wo_body<float>(x2, part, partl, (const float*)Wo, (const float*)bWo,
        (const float*)ao_src, (const float*)ao_dst, (const float*)ao_b,
        Bp2, ssrc2, sdst2, xs, wp, av);
}

// ---------------- K4-new: layer-2 attention split. Grid 512 = 256 rowblocks x
// 2 kb-halves. launch_bounds(1024,4) — natural VGPR should be <=64 for HW
// 2-blocks/CU co-residency (same rationale as k_att1s; no forced cap).
__global__ __launch_bounds__(1024, 4) void k_att2s(
    const unsigned char* __restrict__ bm, const float* __restrict__ ssrc,
    const float* __restrict__ sdst, const short8* __restrict__ Bp,
    float* __restrict__ out2, float* __restrict__ l2p) {
  const int rb = blockIdx.x & 255;
  const int half = blockIdx.x >> 8;
  const int tid = threadIdx.x;
  const int w = tid >> 6;  // j-slice 0..15
  const int lane = tid & 63;
  const int r15 = lane & 15, quad = lane >> 4;
  const int row = rb * 16 + r15;
  const float si = ssrc[row];
  const unsigned char* bmrow = bm + (size_t)row * 512;
  f32x4 acc0 = {0, 0, 0, 0}, acc1 = {0, 0, 0, 0}, acc2 = {0, 0, 0, 0}, acc3 = {0, 0, 0, 0};
  float lsum = 0.f;
  const int kb0 = half * 64 + w * 4;
  {
    int4 ubm = *(const int4*)(bmrow + kb0 * 4);
    int wds[4] = {ubm.x, ubm.y, ubm.z, ubm.w};
#pragma unroll
    for (int kk = 0; kk < 4; kk++) {
      const int kb = kb0 + kk;
      const int j0 = kb * 32 + quad * 8;
      unsigned int bits = (((unsigned int)wds[kk]) >> (quad * 8)) & 0xffu;
      float4 q0 = *(const float4*)(sdst + j0);
      float4 q1 = *(const float4*)(sdst + j0 + 4);
      float sdv[8] = {q0.x, q0.y, q0.z, q0.w, q1.x, q1.y, q1.z, q1.w};
      float pe[8];
#pragma unroll
      for (int jj = 0; jj < 8; jj++) {
        float t = si + sdv[jj];
        float e = __expf(fmaxf(t, 0.2f * t));
        pe[jj] = ((bits >> jj) & 1u) ? e : 0.f;
        lsum += pe[jj];
      }
      i4s8 a;
      a.i.x = cvtpk(pe[0], pe[1]); a.i.y = cvtpk(pe[2], pe[3]);
      a.i.z = cvtpk(pe[4], pe[5]); a.i.w = cvtpk(pe[6], pe[7]);
      const short8* Bk = Bp + (size_t)kb * 256 + lane;
      short8 b0 = Bk[0], b1 = Bk[64], b2 = Bk[128], b3 = Bk[192];
      acc0 = __builtin_amdgcn_mfma_f32_16x16x32_bf16(a.s, b0, acc0, 0, 0, 0);
      acc1 = __builtin_amdgcn_mfma_f32_16x16x32_bf16(a.s, b1, acc1, 0, 0, 0);
      acc2 = __builtin_amdgcn_mfma_f32_16x16x32_bf16(a.s, b2, acc2, 0, 0, 0);
      acc3 = __builtin_amdgcn_mfma_f32_16x16x32_bf16(a.s, b3, acc3, 0, 0, 0);
    }
  }
  lsum += __shfl_xor(lsum, 16);
  lsum += __shfl_xor(lsum, 32);
  __shared__ float accs[8][16][66];
  __shared__ float ls2[8][16];
  if (w >= 8) {
    const int slot = w - 8;
    if (lane < 16) ls2[slot][lane] = lsum;
#pragma unroll
    for (int g = 0; g < 4; g++) {
      int r = quad * 4 + g;
      accs[slot][r][ 0 + r15] = acc0[g];
      accs[slot][r][16 + r15] = acc1[g];
      accs[slot][r][32 + r15] = acc2[g];
      accs[slot][r][48 + r15] = acc3[g];
    }
  }
  __syncthreads();
  if (w < 8) {
    const int slot = w;
    if (lane < 16) ls2[slot][lane] += lsum;
#pragma unroll
    for (int g = 0; g < 4; g++) {
      int r = quad * 4 + g;
      accs[slot][r][ 0 + r15] += acc0[g];
      accs[slot][r][16 + r15] += acc1[g];
      accs[slot][r][32 + r15] += acc2[g];
      accs[slot][r][48 + r15] += acc3[g];
    }
  }
  __syncthreads();
  {
    const int r = tid >> 6, col = tid & 63;
    float s = 0.f, lt = 0.f;
#pragma unroll
    for (int k = 0; k < 8; k++) { s += accs[k][r][col]; lt += ls2[k][r]; }
    out2[((size_t)half * NN + rb * 16 + r) * 64 + col] = s;
    if (col == 0) l2p[(size_t)half * NN + rb * 16 + r] = lt;
  }
}

// ---------------- K4-fin: sum 2 halves, normalize, elu, store.
__global__ __launch_bounds__(256) void k_att2f(const float* __restrict__ out2,
    const float* __restrict__ l2p, const int* __restrict__ flags,
    void* __restrict__ outv) {
  const int idx = blockIdx.x * 256 + threadIdx.x;  // 65536 = 4096 rows x 16 col-quads
  const int row = idx >> 4;
  const int c4 = (idx & 15) * 4;
  float4 a = *(const float4*)(out2 + (size_t)row * 64 + c4);
  float4 b = *(const float4*)(out2 + ((size_t)NN + row) * 64 + c4);
  float lt = l2p[row] + l2p[NN + row];
  float rl = (lt > 0.f) ? 1.f / lt : 0.f;
  float v0 = (a.x + b.x) * rl, v1 = (a.y + b.y) * rl;
  float v2 = (a.z + b.z) * rl, v3 = (a.w + b.w) * rl;
  v0 = v0 > 0.f ? v0 : __expf(v0) - 1.f;
  v1 = v1 > 0.f ? v1 : __expf(v1) - 1.f;
  v2 = v2 > 0.f ? v2 : __expf(v2) - 1.f;
  v3 = v3 > 0.f ? v3 : __expf(v3) - 1.f;
  size_t off = (size_t)row * 64 + c4;
  if (flags[0]) {
    uint2 st; st.x = cvtpk(v0, v1); st.y = cvtpk(v2, v3);
    *(uint2*)((unsigned short*)outv + off) = st;
  } else {
    float4 st; st.x = v0; st.y = v1; st.z = v2; st.w = v3;
    *(float4*)((float*)outv + off) = st;
  }
}

// ---------------- K4-old (fallback): monolithic layer-2 attention.
__global__ __launch_bounds__(1024) void k_att2(
    const unsigned char* __restrict__ bm, const float* __restrict__ ssrc,
    const float* __restrict__ sdst, const short8* __restrict__ Bp,
    const int* __restrict__ flags, void* __restrict__ outv) {
  const int rb = blockIdx.x;
  const int tid = threadIdx.x;
  const int w = tid >> 6;
  const int lane = tid & 63;
  const int r15 = lane & 15, quad = lane >> 4;
  const int row = rb * 16 + r15;
  const float si = ssrc[row];
  const unsigned char* bmrow = bm + (size_t)row * 512;
  f32x4 acc0 = {0, 0, 0, 0}, acc1 = {0, 0, 0, 0}, acc2 = {0, 0, 0, 0}, acc3 = {0, 0, 0, 0};
  float lsum = 0.f;
  const int kb0 = w * 8;
#pragma unroll
  for (int g = 0; g < 2; g++) {
    int4 ubm = *(const int4*)(bmrow + (kb0 + g * 4) * 4);
    int wds[4] = {ubm.x, ubm.y, ubm.z, ubm.w};
#pragma unroll
    for (int kk = 0; kk < 4; kk++) {
      const int kb = kb0 + g * 4 + kk;
      const int j0 = kb * 32 + quad * 8;
      unsigned int bits = (((unsigned int)wds[kk]) >> (quad * 8)) & 0xffu;
      float4 q0 = *(const float4*)(sdst + j0);
      float4 q1 = *(const float4*)(sdst + j0 + 4);
      float sdv[8] = {q0.x, q0.y, q0.z, q0.w, q1.x, q1.y, q1.z, q1.w};
      float pe[8];
#pragma unroll
      for (int jj = 0; jj < 8; jj++) {
        float t = si + sdv[jj];
        float e = __expf(fmaxf(t, 0.2f * t));
        pe[jj] = ((bits >> jj) & 1u) ? e : 0.f;
        lsum += pe[jj];
      }
      i4s8 a;
      a.i.x = cvtpk(pe[0], pe[1]); a.i.y = cvtpk(pe[2], pe[3]);
      a.i.z = cvtpk(pe[4], pe[5]); a.i.w = cvtpk(pe[6], pe[7]);
      const short8* Bk = Bp + (size_t)kb * 256 + lane;
      short8 b0 = Bk[0], b1 = Bk[64], b2 = Bk[128], b3 = Bk[192];
      acc0 = __builtin_amdgcn_mfma_f32_16x16x32_bf16(a.s, b0, acc0, 0, 0, 0);
      acc1 = __builtin_amdgcn_mfma_f32_16x16x32_bf16(a.s, b1, acc1, 0, 0, 0);
      acc2 = __builtin_amdgcn_mfma_f32_16x16x32_bf16(a.s, b2, acc2, 0, 0, 0);
      acc3 = __builtin_amdgcn_mfma_f32_16x16x32_bf16(a.s, b3, acc3, 0, 0, 0);
    }
  }
  lsum += __shfl_xor(lsum, 16);
  lsum += __shfl_xor(lsum, 32);
  __shared__ float accs[8][16][66];
  __shared__ float ls2[8][16];
  if (w >= 8) {
    const int slot = w - 8;
    if (lane < 16) ls2[slot][lane] = lsum;
#pragma unroll
    for (int g = 0; g < 4; g++) {
      int r = quad * 4 + g;
      accs[slot][r][ 0 + r15] = acc0[g];
      accs[slot][r][16 + r15] = acc1[g];
      accs[slot][r][32 + r15] = acc2[g];
      accs[slot][r][48 + r15] = acc3[g];
    }
  }
  __syncthreads();
  if (w < 8) {
    const int slot = w;
    if (lane < 16) ls2[slot][lane] += lsum;
#pragma unroll
    for (int g = 0; g < 4; g++) {
      int r = quad * 4 + g;
      accs[slot][r][ 0 + r15] += acc0[g];
      accs[slot][r][16 + r15] += acc1[g];
      accs[slot][r][32 + r15] += acc2[g];
      accs[slot][r][48 + r15] += acc3[g];
    }
  }
  __syncthreads();
  {
    const int r = tid >> 6, col = tid & 63;
    float s = 0.f, lt = 0.f;
#pragma unroll
    for (int k = 0; k < 8; k++) { s += accs[k][r][col]; lt += ls2[k][r]; }
    float v = (lt > 0.f) ? s / lt : 0.f;
    v = v > 0.f ? v : __expf(v) - 1.f;
    size_t idx = (size_t)(rb * 16 + r) * 64 + col;
    if (flags[0]) ((unsigned short*)outv)[idx] = f2bf(v);
    else          ((float*)outv)[idx] = v;
  }
}

extern "C" void kernel_launch(void* const* d_in, const int* in_sizes, int n_in,
                              void* d_out, int out_size, void* d_ws, size_t ws_size,
                              hipStream_t stream) {
  const void* h      = d_in[0];
  const void* adj    = d_in[1];
  const void* Wh     = d_in[2];
  const void* bWh    = d_in[3];
  const void* a_src  = d_in[4];
  const void* a_dst  = d_in[5];
  const void* a_b    = d_in[6];
  const void* Wo     = d_in[7];
  const void* bWo    = d_in[8];
  const void* ao_src = d_in[9];
  const void* ao_dst = d_in[10];
  const void* ao_b   = d_in[11];

  size_t need_old = 16 + (size_t)NN * 512 + (size_t)NHEADS * NN * HID * 2 +
                    (size_t)NN * 256 * 2 + (size_t)NN * 64 * 2 +
                    (size_t)NHEADS * NN * 8 + (size_t)NN * 8;
  size_t need_new = need_old + (size_t)4 * NN * 256 * 4 + (size_t)16 * NN * 4 +
                    (size_t)2 * NN * 64 * 4 + (size_t)2 * NN * 4;
  if (ws_size < need_old) {
    hipMemsetAsync(d_out, 0x45, (size_t)out_size * 2, stream);
    return;
  }
  const bool big = ws_size >= need_new;
  unsigned char* ws = (unsigned char*)d_ws;
  int* flags = (int*)ws;                        ws += 16;
  unsigned char* bmp = ws;                      ws += (size_t)NN * 512;               // 2 MB
  unsigned short* Bp1 = (unsigned short*)ws;    ws += (size_t)NHEADS * NN * HID * 2;  // 2 MB
  unsigned short* x2  = (unsigned short*)ws;    ws += (size_t)NN * 256 * 2;           // 2 MB
  unsigned short* Bp2 = (unsigned short*)ws;    ws += (size_t)NN * 64 * 2;            // 512 KB
  float* ssrc1 = (float*)ws;                    ws += (size_t)NHEADS * NN * 4;
  float* sdst1 = (float*)ws;                    ws += (size_t)NHEADS * NN * 4;
  float* ssrc2 = (float*)ws;                    ws += (size_t)NN * 4;
  float* sdst2 = (float*)ws;                    ws += (size_t)NN * 4;
  float* part  = (float*)ws;                    ws += (size_t)4 * NN * 256 * 4;       // 16 MB
  float* partl = (float*)ws;                    ws += (size_t)16 * NN * 4;            // 256 KB
  float* out2  = (float*)ws;                    ws += (size_t)2 * NN * 64 * 4;        // 2 MB
  float* l2p   = (float*)ws;                    ws += (size_t)2 * NN * 4;             // 32 KB

  k_bm   <<<dim3(4096), dim3(256),  0, stream>>>(adj, h, flags, bmp);
  k_wh   <<<dim3(256),  dim3(1024), 0, stream>>>(h, Wh, bWh, a_src, a_dst, a_b, flags,
                                                 Bp1, ssrc1, sdst1);
  if (big) {
    k_att1s<<<dim3(512), dim3(1024), 0, stream>>>(bmp, ssrc1, sdst1, (const short8*)Bp1,
                                                  part, partl);
    k_wo   <<<dim3(256), dim3(1024), 0, stream>>>(x2, part, partl, Wo, bWo, ao_src, ao_dst,
                                                  ao_b, flags, Bp2, ssrc2, sdst2);
    k_att2s<<<dim3(512), dim3(1024), 0, stream>>>(bmp, ssrc2, sdst2, (const short8*)Bp2,
                                                  out2, l2p);
    k_att2f<<<dim3(256), dim3(256),  0, stream>>>(out2, l2p, flags, d_out);
  } else {
    k_att1 <<<dim3(256), dim3(1024), 0, stream>>>(bmp, ssrc1, sdst1, (const short8*)Bp1, x2);
    k_wo   <<<dim3(256), dim3(1024), 0, stream>>>(x2, (const float*)nullptr,
                                                  (const float*)nullptr, Wo, bWo, ao_src,
                                                  ao_dst, ao_b, flags, Bp2, ssrc2, sdst2);
    k_att2 <<<dim3(256), dim3(1024), 0, stream>>>(bmp, ssrc2, sdst2, (const short8*)Bp2,
                                                  flags, d_out);
  }
}

// Round 11
// 186.479 us; speedup vs baseline: 1.8218x; 1.0005x over previous
//
#include <hip/hip_runtime.h>

#define NN 4096
#define NHEADS 4
#define HID 64
#define INDIM 256
#define LOG2E 1.4426950408889634f

using short8 = __attribute__((ext_vector_type(8))) short;
using f32x4  = __attribute__((ext_vector_type(4))) float;

union f32u { float f; unsigned int u; };
union i4s8 { int4 i; short8 s; };

__device__ __forceinline__ float bf2f(unsigned short s) {
  f32u x; x.u = ((unsigned int)s) << 16; return x.f;
}
__device__ __forceinline__ unsigned short f2bf(float f) {
  f32u x; x.f = f;
  unsigned int r = x.u + 0x7fffu + ((x.u >> 16) & 1u);
  return (unsigned short)(r >> 16);
}
// packed f32x2 -> bf16x2 (RNE, same as f2bf) in one instruction
__device__ __forceinline__ unsigned int cvtpk(float lo, float hi) {
  unsigned int r;
  asm("v_cvt_pk_bf16_f32 %0, %1, %2" : "=v"(r) : "v"(lo), "v"(hi));
  return r;
}

// overloaded external-input loaders
__device__ __forceinline__ float ld(const unsigned short* p, size_t i) { return bf2f(p[i]); }
__device__ __forceinline__ float ld(const float* p, size_t i) { return p[i]; }
// 4-element loader (8B for bf16, 16B for fp32) — p must be 4-elem aligned
__device__ __forceinline__ void ld4(const unsigned short* p, float* out) {
  short4 v = *(const short4*)p;
  out[0] = bf2f((unsigned short)v.x); out[1] = bf2f((unsigned short)v.y);
  out[2] = bf2f((unsigned short)v.z); out[3] = bf2f((unsigned short)v.w);
}
__device__ __forceinline__ void ld4(const float* p, float* out) {
  float4 a = *(const float4*)p;
  out[0] = a.x; out[1] = a.y; out[2] = a.z; out[3] = a.w;
}

// ---------------- K0: adj -> bitmask bytes bm[i][j>>3]; dtype probe folded in.
__global__ __launch_bounds__(256) void k_bm(const void* adjv, const void* hv,
                                            int* __restrict__ flags,
                                            unsigned char* __restrict__ bm) {
  __shared__ int s_at;
  const int tid = threadIdx.x;
  if (tid == 0) s_at = 0;
  __syncthreads();
  const unsigned int* au = (const unsigned int*)adjv;
  unsigned int wv = au[tid];
  if ((wv & 0xFFFFu) == 0x3F80u) atomicOr(&s_at, 2);       // bf16 pair (1.0, x)
  else if (wv == 0x3F800000u) atomicOr(&s_at, 1);          // float32 1.0
  __syncthreads();
  const int at = (s_at & 2) ? 2 : (s_at & 1);
  const int i = blockIdx.x;
  if (i == 0 && tid < 64) {
    const unsigned short* hu = (const unsigned short*)hv;
    int bad = 0;
    for (int t = tid; t < 256; t += 64) {
      float v = bf2f(hu[t]);
      if (!(v > -1000.f && v < 1000.f)) bad = 1;           // fp32 halves look huge as bf16
    }
    unsigned long long m = __ballot(bad);
    if (tid == 0) { flags[0] = m ? 0 : 1; flags[1] = at; }
  }
#pragma unroll
  for (int rep = 0; rep < 2; rep++) {
    int jb = tid + rep * 256;
    unsigned int b = 0;
    if (at == 0) {
      const int4* arow = (const int4*)((const int*)adjv + (size_t)i * NN);
      int4 a0 = arow[jb * 2 + 0];
      int4 a1 = arow[jb * 2 + 1];
      b |= (a0.x > 0) ? 1u : 0u;  b |= (a0.y > 0) ? 2u : 0u;
      b |= (a0.z > 0) ? 4u : 0u;  b |= (a0.w > 0) ? 8u : 0u;
      b |= (a1.x > 0) ? 16u : 0u; b |= (a1.y > 0) ? 32u : 0u;
      b |= (a1.z > 0) ? 64u : 0u; b |= (a1.w > 0) ? 128u : 0u;
    } else if (at == 1) {
      const float* arow = (const float*)adjv + (size_t)i * NN + jb * 8;
      for (int t = 0; t < 8; t++) b |= (arow[t] > 0.5f) ? (1u << t) : 0u;
    } else {
      const unsigned short* arow = (const unsigned short*)adjv + (size_t)i * NN + jb * 8;
      for (int t = 0; t < 8; t++) b |= (bf2f(arow[t]) > 0.5f) ? (1u << t) : 0u;
    }
    bm[(size_t)i * 512 + jb] = (unsigned char)b;
  }
}

// ---------------- K1: wh = h@Wh + bWh. LDS-staged h tile (16x256), 16 waves =
// 4 heads x 4 k-quarters, two-slot LDS combine, pack phase writes int4 Bp1 units.
// ssrc/sdst pre-scaled by LOG2E so attention kernels use exp2 directly.
template <typename T>
__device__ __forceinline__ void wh_body(const T* h, const T* Wh, const T* bWh,
    const T* a_src, const T* a_dst, const T* a_b,
    unsigned short* __restrict__ Bp1, float* __restrict__ ssrc1, float* __restrict__ sdst1,
    float (*hs)[260], float (*wp)[16][260], float* av0, float* av1) {
  const int tid = threadIdx.x;
  const int w = tid >> 6, lane = tid & 63;
  const int head = w & 3, kq = w >> 2;
  const int rb = blockIdx.x;       // 0..255, 16 rows each
  const int R0 = rb * 16;
  const int d = lane;
  {
    const int r = tid >> 6, c4 = (tid & 63) * 4;
    float hv4[4];
    ld4(h + (size_t)(R0 + r) * 256 + c4, hv4);
    hs[r][c4 + 0] = hv4[0]; hs[r][c4 + 1] = hv4[1];
    hs[r][c4 + 2] = hv4[2]; hs[r][c4 + 3] = hv4[3];
  }
  if (tid < 256) av0[tid] = ld(a_src, tid);
  else if (tid < 512) av1[tid - 256] = ld(a_dst, tid - 256);
  __syncthreads();
  float acc[16];
  float bv = (kq == 0) ? ld(bWh, head * 64 + d) : 0.f;
#pragma unroll
  for (int r = 0; r < 16; r++) acc[r] = bv;
  const int k0 = kq * 64;
  for (int kb = 0; kb < 8; kb++) {
    float wv[8];
#pragma unroll
    for (int j = 0; j < 8; j++)
      wv[j] = ld(Wh, (size_t)(head * 256 + k0 + kb * 8 + j) * 64 + d);
#pragma unroll
    for (int r = 0; r < 16; r++) {
      float4 ha = *(const float4*)(&hs[r][k0 + kb * 8]);
      float4 hb = *(const float4*)(&hs[r][k0 + kb * 8 + 4]);
      acc[r] = fmaf(ha.x, wv[0], acc[r]);
      acc[r] = fmaf(ha.y, wv[1], acc[r]);
      acc[r] = fmaf(ha.z, wv[2], acc[r]);
      acc[r] = fmaf(ha.w, wv[3], acc[r]);
      acc[r] = fmaf(hb.x, wv[4], acc[r]);
      acc[r] = fmaf(hb.y, wv[5], acc[r]);
      acc[r] = fmaf(hb.z, wv[6], acc[r]);
      acc[r] = fmaf(hb.w, wv[7], acc[r]);
    }
  }
  if (kq >= 2) {
#pragma unroll
    for (int r = 0; r < 16; r++) wp[kq - 2][r][head * 64 + d] = acc[r];
  }
  __syncthreads();
  if (kq < 2) {
#pragma unroll
    for (int r = 0; r < 16; r++) wp[kq][r][head * 64 + d] += acc[r];
  }
  __syncthreads();
  if (tid < 512) {
    const int hh = tid >> 7, tt = (tid >> 5) & 3, lnh = tid & 31;
    const int q2 = (rb & 1) * 2 + (lnh >> 4);
    const int ln = q2 * 16 + (lnh & 15);
    const int dd = tt * 16 + (lnh & 15);
    const int rbase = (lnh >> 4) * 8;
    float v[8];
#pragma unroll
    for (int jj = 0; jj < 8; jj++)
      v[jj] = wp[0][rbase + jj][hh * 64 + dd] + wp[1][rbase + jj][hh * 64 + dd];
    i4s8 s;
    s.i.x = cvtpk(v[0], v[1]); s.i.y = cvtpk(v[2], v[3]);
    s.i.z = cvtpk(v[4], v[5]); s.i.w = cvtpk(v[6], v[7]);
    const int kb = rb >> 1;
    *(int4*)(Bp1 + ((((size_t)hh * 128 + kb) * 4 + tt) * 64 + ln) * 8) = s.i;
  } else if (tid < 576) {
    const int t2 = tid - 512;
    const int hh = t2 >> 4, r = t2 & 15;
    float ps = 0.f, pd = 0.f;
    for (int c = 0; c < 64; c++) {
      float wv2 = wp[0][r][hh * 64 + c] + wp[1][r][hh * 64 + c];
      ps = fmaf(wv2, av0[hh * 64 + c], ps);
      pd = fmaf(wv2, av1[hh * 64 + c], pd);
    }
    ssrc1[hh * NN + R0 + r] = (ps + ld(a_b, hh)) * LOG2E;
    sdst1[hh * NN + R0 + r] = pd * LOG2E;
  }
}
__global__ __launch_bounds__(1024, 4) void k_wh(const void* h, const void* Wh, const void* bWh,
    const void* a_src, const void* a_dst, const void* a_b, const int* __restrict__ flags,
    unsigned short* Bp1, float* ssrc1, float* sdst1) {
  __shared__ float hs[16][260];
  __shared__ float wp[2][16][260];
  __shared__ float av0[256], av1[256];
  if (flags[0])
    wh_body<unsigned short>((const unsigned short*)h, (const unsigned short*)Wh,
        (const unsigned short*)bWh, (const unsigned short*)a_src,
        (const unsigned short*)a_dst, (const unsigned short*)a_b, Bp1, ssrc1, sdst1,
        hs, wp, av0, av1);
  else
    wh_body<float>((const float*)h, (const float*)Wh, (const float*)bWh, (const float*)a_src,
        (const float*)a_dst, (const float*)a_b, Bp1, ssrc1, sdst1, hs, wp, av0, av1);
}

// ---------------- K2: layer-1 attention. Grid 256 = 128 rowblocks(32 rows) x 2 kb-halves.
// 1024 thr = 16 waves = 4 heads x 4 slices(16 kb). Two A-frags/wave share every B load.
// Round-10 lesson: higher occupancy via kb-split gives ~0 gain; keep this structure.
__global__ __launch_bounds__(1024, 4) void k_att1s(
    const unsigned char* __restrict__ bm, const float* __restrict__ ssrc,
    const float* __restrict__ sdst, const short8* __restrict__ Bp,
    float* __restrict__ part, float* __restrict__ partl) {
  const int rb = blockIdx.x & 127;
  const int half = blockIdx.x >> 7;
  const int tid = threadIdx.x;
  const int w = tid >> 6;
  const int head = w & 3;
  const int sl = w >> 2;  // 0..3: 16-kb slice within this half
  const int lane = tid & 63;
  const int r15 = lane & 15, quad = lane >> 4;
  const int row0 = rb * 32 + r15;
  const int row1 = row0 + 16;
  const float si0 = ssrc[head * NN + row0];
  const float si1 = ssrc[head * NN + row1];
  const unsigned char* bmr0 = bm + (size_t)row0 * 512;
  const unsigned char* bmr1 = bm + (size_t)row1 * 512;
  const float* sd = sdst + head * NN;
  const short8* Bh = Bp + (size_t)head * 128 * 4 * 64;
  f32x4 acc0[4], acc1[4];
#pragma unroll
  for (int t = 0; t < 4; t++) { acc0[t] = (f32x4){0,0,0,0}; acc1[t] = (f32x4){0,0,0,0}; }
  float ls0 = 0.f, ls1 = 0.f;
  const int kb0 = half * 64 + sl * 16;
  for (int g = 0; g < 4; g++) {          // 4 kb per group, bm fetched as int4
    const int kbg = kb0 + g * 4;
    int4 u0 = *(const int4*)(bmr0 + kbg * 4);
    int4 u1 = *(const int4*)(bmr1 + kbg * 4);
    int wd0[4] = {u0.x, u0.y, u0.z, u0.w};
    int wd1[4] = {u1.x, u1.y, u1.z, u1.w};
#pragma unroll
    for (int kk = 0; kk < 4; kk++) {
      const int kb = kbg + kk;
      const int j0 = kb * 32 + quad * 8;
      float4 q0 = *(const float4*)(sd + j0);
      float4 q1 = *(const float4*)(sd + j0 + 4);
      float sdv[8] = {q0.x, q0.y, q0.z, q0.w, q1.x, q1.y, q1.z, q1.w};
      unsigned int bits0 = (((unsigned int)wd0[kk]) >> (quad * 8)) & 0xffu;
      unsigned int bits1 = (((unsigned int)wd1[kk]) >> (quad * 8)) & 0xffu;
      float pe0[8], pe1[8];
#pragma unroll
      for (int jj = 0; jj < 8; jj++) {
        float t0 = si0 + sdv[jj];
        float e0 = exp2f(fmaxf(t0, 0.2f * t0));   // inputs pre-scaled by LOG2E
        pe0[jj] = ((bits0 >> jj) & 1u) ? e0 : 0.f;
        ls0 += pe0[jj];
        float t1 = si1 + sdv[jj];
        float e1 = exp2f(fmaxf(t1, 0.2f * t1));
        pe1[jj] = ((bits1 >> jj) & 1u) ? e1 : 0.f;
        ls1 += pe1[jj];
      }
      i4s8 a0, a1;
      a0.i.x = cvtpk(pe0[0], pe0[1]); a0.i.y = cvtpk(pe0[2], pe0[3]);
      a0.i.z = cvtpk(pe0[4], pe0[5]); a0.i.w = cvtpk(pe0[6], pe0[7]);
      a1.i.x = cvtpk(pe1[0], pe1[1]); a1.i.y = cvtpk(pe1[2], pe1[3]);
      a1.i.z = cvtpk(pe1[4], pe1[5]); a1.i.w = cvtpk(pe1[6], pe1[7]);
      const short8* Bk = Bh + (size_t)kb * 256 + lane;
      short8 bt[4];
      bt[0] = Bk[0]; bt[1] = Bk[64]; bt[2] = Bk[128]; bt[3] = Bk[192];
#pragma unroll
      for (int t = 0; t < 4; t++) {
        acc0[t] = __builtin_amdgcn_mfma_f32_16x16x32_bf16(a0.s, bt[t], acc0[t], 0, 0, 0);
        acc1[t] = __builtin_amdgcn_mfma_f32_16x16x32_bf16(a1.s, bt[t], acc1[t], 0, 0, 0);
      }
    }
  }
  ls0 += __shfl_xor(ls0, 16); ls0 += __shfl_xor(ls0, 32);
  ls1 += __shfl_xor(ls1, 16); ls1 += __shfl_xor(ls1, 32);
  __shared__ float accs[8][16][66];
  __shared__ float lsh[8][16];
#define DOPASS(AC, LSV, PASS)                                                  \
  do {                                                                         \
    if (sl >= 2) {                                                             \
      const int slot = head * 2 + (sl - 2);                                    \
      if (lane < 16) lsh[slot][lane] = (LSV);                                  \
      _Pragma("unroll") for (int t = 0; t < 4; t++)                            \
        _Pragma("unroll") for (int gg = 0; gg < 4; gg++)                       \
          accs[slot][quad * 4 + gg][t * 16 + r15] = (AC)[t][gg];               \
    }                                                                          \
    __syncthreads();                                                           \
    if (sl < 2) {                                                              \
      const int slot = head * 2 + sl;                                          \
      if (lane < 16) lsh[slot][lane] += (LSV);                                 \
      _Pragma("unroll") for (int t = 0; t < 4; t++)                            \
        _Pragma("unroll") for (int gg = 0; gg < 4; gg++)                       \
          accs[slot][quad * 4 + gg][t * 16 + r15] += (AC)[t][gg];              \
    }                                                                          \
    __syncthreads();                                                           \
    _Pragma("unroll") for (int idx = tid; idx < 4096; idx += 1024) {           \
      int r = idx >> 8, hc = idx & 255;                                        \
      int hh = hc >> 6, col = hc & 63;                                         \
      part[((size_t)half * NN + rb * 32 + (PASS) * 16 + r) * 256 + hc] =       \
          accs[hh * 2][r][col] + accs[hh * 2 + 1][r][col];                     \
    }                                                                          \
    if (tid < 64)                                                              \
      partl[((size_t)half * 4 + (tid >> 4)) * NN + rb * 32 + (PASS) * 16 +     \
            (tid & 15)] = lsh[(tid >> 4) * 2][tid & 15] +                      \
                          lsh[(tid >> 4) * 2 + 1][tid & 15];                   \
    __syncthreads();                                                           \
  } while (0)
  DOPASS(acc0, ls0, 0);
  DOPASS(acc1, ls1, 1);
#undef DOPASS
}

// ---------------- K2-old (fallback if workspace too small for partials)
__global__ __launch_bounds__(1024) void k_att1(
    const unsigned char* __restrict__ bm, const float* __restrict__ ssrc,
    const float* __restrict__ sdst, const short8* __restrict__ Bp,
    unsigned short* __restrict__ x2) {
  const int rb = blockIdx.x;
  const int tid = threadIdx.x;
  const int w = tid >> 6;
  const int head = w & 3;
  const int slice = w >> 2;
  const int lane = tid & 63;
  const int r15 = lane & 15, quad = lane >> 4;
  const int row = rb * 16 + r15;
  const float si = ssrc[head * NN + row];
  const unsigned char* bmrow = bm + (size_t)row * 512;
  const float* sd = sdst + head * NN;
  const short8* Bh = Bp + (size_t)head * 128 * 4 * 64;
  f32x4 acc0 = {0, 0, 0, 0}, acc1 = {0, 0, 0, 0}, acc2 = {0, 0, 0, 0}, acc3 = {0, 0, 0, 0};
  float lsum = 0.f;
  const int kb0 = slice * 32;
  for (int kb = kb0; kb < kb0 + 32; kb++) {
    const int j0 = kb * 32 + quad * 8;
    unsigned int bits = bmrow[kb * 4 + quad];
    float4 q0 = *(const float4*)(sd + j0);
    float4 q1 = *(const float4*)(sd + j0 + 4);
    float sdv[8] = {q0.x, q0.y, q0.z, q0.w, q1.x, q1.y, q1.z, q1.w};
    short8 af;
#pragma unroll
    for (int jj = 0; jj < 8; jj++) {
      float t = si + sdv[jj];
      float lr = fmaxf(t, 0.2f * t);
      float e = exp2f(lr);
      float pe = ((bits >> jj) & 1u) ? e : 0.0f;
      lsum += pe;
      af[jj] = (short)f2bf(pe);
    }
    const short8* Bk = Bh + (size_t)kb * 256 + lane;
    short8 b0 = Bk[0], b1 = Bk[64], b2 = Bk[128], b3 = Bk[192];
    acc0 = __builtin_amdgcn_mfma_f32_16x16x32_bf16(af, b0, acc0, 0, 0, 0);
    acc1 = __builtin_amdgcn_mfma_f32_16x16x32_bf16(af, b1, acc1, 0, 0, 0);
    acc2 = __builtin_amdgcn_mfma_f32_16x16x32_bf16(af, b2, acc2, 0, 0, 0);
    acc3 = __builtin_amdgcn_mfma_f32_16x16x32_bf16(af, b3, acc3, 0, 0, 0);
  }
  lsum += __shfl_xor(lsum, 16);
  lsum += __shfl_xor(lsum, 32);
  __shared__ float accs[8][16][66];
  __shared__ float ls[8][16];
  if (slice >= 2) {
    const int slot = w - 8;
    if (lane < 16) ls[slot][lane] = lsum;
#pragma unroll
    for (int g = 0; g < 4; g++) {
      int r = quad * 4 + g;
      accs[slot][r][ 0 + r15] = acc0[g];
      accs[slot][r][16 + r15] = acc1[g];
      accs[slot][r][32 + r15] = acc2[g];
      accs[slot][r][48 + r15] = acc3[g];
    }
  }
  __syncthreads();
  if (slice < 2) {
    const int slot = w;
    if (lane < 16) ls[slot][lane] += lsum;
#pragma unroll
    for (int g = 0; g < 4; g++) {
      int r = quad * 4 + g;
      accs[slot][r][ 0 + r15] += acc0[g];
      accs[slot][r][16 + r15] += acc1[g];
      accs[slot][r][32 + r15] += acc2[g];
      accs[slot][r][48 + r15] += acc3[g];
    }
  }
  __syncthreads();
#pragma unroll
  for (int c = tid; c < 4096; c += 1024) {
    int r = c >> 8, hc = c & 255;
    int hh = hc >> 6, col = hc & 63;
    float s = accs[hh][r][col] + accs[hh + 4][r][col];
    float lt = ls[hh][r] + ls[hh + 4][r];
    float v = (lt > 0.f) ? s / lt : 0.f;
    v = v > 0.f ? v : __expf(v) - 1.f;
    x2[(size_t)(rb * 16 + r) * 256 + hc] = f2bf(v);
  }
}

// ---------------- K3: wo = x2@Wo + bWo. Big path stages from 2-half part/partl
// (half-sum + normalize + elu inline); fallback path (part==nullptr) stages from x2.
template <typename T>
__device__ __forceinline__ void wo_body(const unsigned short* x2,
    const float* part, const float* partl,
    const T* Wo, const T* bWo, const T* ao_src, const T* ao_dst, const T* ao_b,
    unsigned short* __restrict__ Bp2, float* __restrict__ ssrc2, float* __restrict__ sdst2,
    float (*xs)[260], float (*wp)[16][68], float* av) {
  const int tid = threadIdx.x;
  const int w = tid >> 6, lane = tid & 63;
  const int rg = w & 3, kq = w >> 2;
  const int rb = blockIdx.x;         // 0..255, 16 rows each
  const int d = lane;
  {
    const int r = tid >> 6, c4 = (tid & 63) * 4;
    const int row = rb * 16 + r;
    if (part) {
      float4 p0 = *(const float4*)(part + (size_t)row * 256 + c4);
      float4 p1 = *(const float4*)(part + (size_t)NN * 256 + (size_t)row * 256 + c4);
      const int head = c4 >> 6;
      float lt = partl[(size_t)head * NN + row] + partl[(size_t)(4 + head) * NN + row];
      float rl = (lt > 0.f) ? 1.f / lt : 0.f;
      float v0 = (p0.x + p1.x) * rl, v1 = (p0.y + p1.y) * rl;
      float v2 = (p0.z + p1.z) * rl, v3 = (p0.w + p1.w) * rl;
      v0 = v0 > 0.f ? v0 : __expf(v0) - 1.f;
      v1 = v1 > 0.f ? v1 : __expf(v1) - 1.f;
      v2 = v2 > 0.f ? v2 : __expf(v2) - 1.f;
      v3 = v3 > 0.f ? v3 : __expf(v3) - 1.f;
      xs[r][c4 + 0] = v0; xs[r][c4 + 1] = v1;
      xs[r][c4 + 2] = v2; xs[r][c4 + 3] = v3;
    } else {
      float hv4[4];
      ld4(x2 + (size_t)row * 256 + c4, hv4);
      xs[r][c4 + 0] = hv4[0]; xs[r][c4 + 1] = hv4[1];
      xs[r][c4 + 2] = hv4[2]; xs[r][c4 + 3] = hv4[3];
    }
  }
  if (tid < 64) av[tid] = ld(ao_src, tid);
  else if (tid < 128) av[tid] = ld(ao_dst, tid - 64);
  __syncthreads();
  const int rr = rg * 4;             // this wave's 4 local rows
  float acc[4];
  float bv = (kq == 0) ? ld(bWo, d) : 0.f;
#pragma unroll
  for (int r = 0; r < 4; r++) acc[r] = bv;
  const int k0 = kq * 64;
  for (int kb = 0; kb < 8; kb++) {
    float wv[8];
#pragma unroll
    for (int j = 0; j < 8; j++)
      wv[j] = ld(Wo, (size_t)(k0 + kb * 8 + j) * 64 + d);
#pragma unroll
    for (int r = 0; r < 4; r++) {
      float4 ha = *(const float4*)(&xs[rr + r][k0 + kb * 8]);
      float4 hb = *(const float4*)(&xs[rr + r][k0 + kb * 8 + 4]);
      acc[r] = fmaf(ha.x, wv[0], acc[r]);
      acc[r] = fmaf(ha.y, wv[1], acc[r]);
      acc[r] = fmaf(ha.z, wv[2], acc[r]);
      acc[r] = fmaf(ha.w, wv[3], acc[r]);
      acc[r] = fmaf(hb.x, wv[4], acc[r]);
      acc[r] = fmaf(hb.y, wv[5], acc[r]);
      acc[r] = fmaf(hb.z, wv[6], acc[r]);
      acc[r] = fmaf(hb.w, wv[7], acc[r]);
    }
  }
  if (kq >= 2) {
#pragma unroll
    for (int r = 0; r < 4; r++) wp[kq - 2][rr + r][d] = acc[r];
  }
  __syncthreads();
  if (kq < 2) {
#pragma unroll
    for (int r = 0; r < 4; r++) wp[kq][rr + r][d] += acc[r];
  }
  __syncthreads();
  if (tid < 128) {
    const int tt = tid >> 5, lnh = tid & 31;
    const int q2 = (rb & 1) * 2 + (lnh >> 4);
    const int ln = q2 * 16 + (lnh & 15);
    const int dd = tt * 16 + (lnh & 15);
    const int rbase = (lnh >> 4) * 8;
    float v[8];
#pragma unroll
    for (int jj = 0; jj < 8; jj++)
      v[jj] = wp[0][rbase + jj][dd] + wp[1][rbase + jj][dd];
    i4s8 s;
    s.i.x = cvtpk(v[0], v[1]); s.i.y = cvtpk(v[2], v[3]);
    s.i.z = cvtpk(v[4], v[5]); s.i.w = cvtpk(v[6], v[7]);
    const int kb = rb >> 1;
    *(int4*)(Bp2 + (((size_t)kb * 4 + tt) * 64 + ln) * 8) = s.i;
  } else if (tid < 144) {
    const int r = tid - 128;
    float ps = 0.f, pd = 0.f;
    for (int c = 0; c < 64; c++) {
      float wv2 = wp[0][r][c] + wp[1][r][c];
      ps = fmaf(wv2, av[c], ps);
      pd = fmaf(wv2, av[64 + c], pd);
    }
    ssrc2[(size_t)rb * 16 + r] = (ps + ld(ao_b, 0)) * LOG2E;
    sdst2[(size_t)rb * 16 + r] = pd * LOG2E;
  }
}
__global__ __launch_bounds__(1024, 4) void k_wo(const unsigned short* __restrict__ x2,
    const float* __restrict__ part, const float* __restrict__ partl,
    const void* Wo, const void* bWo, const void* ao_src, const void* ao_dst, const void* ao_b,
    const int* __restrict__ flags, unsigned short* Bp2, float* ssrc2, float* sdst2) {
  __shared__ float xs[16][260];
  __shared__ float wp[2][16][68];
  __shared__ float av[128];
  if (flags[0])
    wo_body<unsigned short>(x2, part, partl, (const unsigned short*)Wo,
        (const unsigned short*)bWo, (const unsigned short*)ao_src,
        (const unsigned short*)ao_dst, (const unsigned short*)ao_b,
        Bp2, ssrc2, sdst2, xs, wp, av);
  else
    wo_body<float>(x2, part, partl, (const float*)Wo, (const float*)bWo,
        (const float*)ao_src, (const float*)ao_dst, (const float*)ao_b,
        Bp2, ssrc2, sdst2, xs, wp, av);
}

// ---------------- K4: layer-2 attention (1 head), 16 rows/block, 16-way j-split.
__global__ __launch_bounds__(1024) void k_att2(
    const unsigned char* __restrict__ bm, const float* __restrict__ ssrc,
    const float* __restrict__ sdst, const short8* __restrict__ Bp,
    const int* __restrict__ flags, void* __restrict__ outv) {
  const int rb = blockIdx.x;
  const int tid = threadIdx.x;
  const int w = tid >> 6;  // j-slice 0..15
  const int lane = tid & 63;
  const int r15 = lane & 15, quad = lane >> 4;
  const int row = rb * 16 + r15;
  const float si = ssrc[row];
  const unsigned char* bmrow = bm + (size_t)row * 512;
  f32x4 acc0 = {0, 0, 0, 0}, acc1 = {0, 0, 0, 0}, acc2 = {0, 0, 0, 0}, acc3 = {0, 0, 0, 0};
  float lsum = 0.f;
  const int kb0 = w * 8;
#pragma unroll
  for (int g = 0; g < 2; g++) {
    int4 ubm = *(const int4*)(bmrow + (kb0 + g * 4) * 4);
    int wds[4] = {ubm.x, ubm.y, ubm.z, ubm.w};
#pragma unroll
    for (int kk = 0; kk < 4; kk++) {
      const int kb = kb0 + g * 4 + kk;
      const int j0 = kb * 32 + quad * 8;
      unsigned int bits = (((unsigned int)wds[kk]) >> (quad * 8)) & 0xffu;
      float4 q0 = *(const float4*)(sdst + j0);
      float4 q1 = *(const float4*)(sdst + j0 + 4);
      float sdv[8] = {q0.x, q0.y, q0.z, q0.w, q1.x, q1.y, q1.z, q1.w};
      float pe[8];
#pragma unroll
      for (int jj = 0; jj < 8; jj++) {
        float t = si + sdv[jj];
        float e = exp2f(fmaxf(t, 0.2f * t));   // inputs pre-scaled by LOG2E
        pe[jj] = ((bits >> jj) & 1u) ? e : 0.f;
        lsum += pe[jj];
      }
      i4s8 a;
      a.i.x = cvtpk(pe[0], pe[1]); a.i.y = cvtpk(pe[2], pe[3]);
      a.i.z = cvtpk(pe[4], pe[5]); a.i.w = cvtpk(pe[6], pe[7]);
      const short8* Bk = Bp + (size_t)kb * 256 + lane;
      short8 b0 = Bk[0], b1 = Bk[64], b2 = Bk[128], b3 = Bk[192];
      acc0 = __builtin_amdgcn_mfma_f32_16x16x32_bf16(a.s, b0, acc0, 0, 0, 0);
      acc1 = __builtin_amdgcn_mfma_f32_16x16x32_bf16(a.s, b1, acc1, 0, 0, 0);
      acc2 = __builtin_amdgcn_mfma_f32_16x16x32_bf16(a.s, b2, acc2, 0, 0, 0);
      acc3 = __builtin_amdgcn_mfma_f32_16x16x32_bf16(a.s, b3, acc3, 0, 0, 0);
    }
  }
  lsum += __shfl_xor(lsum, 16);
  lsum += __shfl_xor(lsum, 32);
  __shared__ float accs[8][16][66];
  __shared__ float ls2[8][16];
  if (w >= 8) {
    const int slot = w - 8;
    if (lane < 16) ls2[slot][lane] = lsum;
#pragma unroll
    for (int g = 0; g < 4; g++) {
      int r = quad * 4 + g;
      accs[slot][r][ 0 + r15] = acc0[g];
      accs[slot][r][16 + r15] = acc1[g];
      accs[slot][r][32 + r15] = acc2[g];
      accs[slot][r][48 + r15] = acc3[g];
    }
  }
  __syncthreads();
  if (w < 8) {
    const int slot = w;
    if (lane < 16) ls2[slot][lane] += lsum;
#pragma unroll
    for (int g = 0; g < 4; g++) {
      int r = quad * 4 + g;
      accs[slot][r][ 0 + r15] += acc0[g];
      accs[slot][r][16 + r15] += acc1[g];
      accs[slot][r][32 + r15] += acc2[g];
      accs[slot][r][48 + r15] += acc3[g];
    }
  }
  __syncthreads();
  {
    const int r = tid >> 6, col = tid & 63;
    float s = 0.f, lt = 0.f;
#pragma unroll
    for (int k = 0; k < 8; k++) { s += accs[k][r][col]; lt += ls2[k][r]; }
    float v = (lt > 0.f) ? s / lt : 0.f;
    v = v > 0.f ? v : __expf(v) - 1.f;
    size_t idx = (size_t)(rb * 16 + r) * 64 + col;
    if (flags[0]) ((unsigned short*)outv)[idx] = f2bf(v);
    else          ((float*)outv)[idx] = v;
  }
}

extern "C" void kernel_launch(void* const* d_in, const int* in_sizes, int n_in,
                              void* d_out, int out_size, void* d_ws, size_t ws_size,
                              hipStream_t stream) {
  const void* h      = d_in[0];
  const void* adj    = d_in[1];
  const void* Wh     = d_in[2];
  const void* bWh    = d_in[3];
  const void* a_src  = d_in[4];
  const void* a_dst  = d_in[5];
  const void* a_b    = d_in[6];
  const void* Wo     = d_in[7];
  const void* bWo    = d_in[8];
  const void* ao_src = d_in[9];
  const void* ao_dst = d_in[10];
  const void* ao_b   = d_in[11];

  size_t need_old = 16 + (size_t)NN * 512 + (size_t)NHEADS * NN * HID * 2 +
                    (size_t)NN * 256 * 2 + (size_t)NN * 64 * 2 +
                    (size_t)NHEADS * NN * 8 + (size_t)NN * 8;
  size_t need_new = need_old + (size_t)2 * NN * 256 * 4 + (size_t)2 * 4 * NN * 4;
  if (ws_size < need_old) {
    // Distinct signature if workspace is too small (bf16 0x4545 = 789).
    hipMemsetAsync(d_out, 0x45, (size_t)out_size * 2, stream);
    return;
  }
  const bool big = ws_size >= need_new;
  unsigned char* ws = (unsigned char*)d_ws;
  int* flags = (int*)ws;                        ws += 16;
  unsigned char* bmp = ws;                      ws += (size_t)NN * 512;               // 2 MB
  unsigned short* Bp1 = (unsigned short*)ws;    ws += (size_t)NHEADS * NN * HID * 2;  // 2 MB
  unsigned short* x2  = (unsigned short*)ws;    ws += (size_t)NN * 256 * 2;           // 2 MB
  unsigned short* Bp2 = (unsigned short*)ws;    ws += (size_t)NN * 64 * 2;            // 512 KB
  float* ssrc1 = (float*)ws;                    ws += (size_t)NHEADS * NN * 4;
  float* sdst1 = (float*)ws;                    ws += (size_t)NHEADS * NN * 4;
  float* ssrc2 = (float*)ws;                    ws += (size_t)NN * 4;
  float* sdst2 = (float*)ws;                    ws += (size_t)NN * 4;
  float* part  = (float*)ws;                    ws += (size_t)2 * NN * 256 * 4;       // 8 MB
  float* partl = (float*)ws;                    ws += (size_t)2 * 4 * NN * 4;         // 128 KB

  k_bm   <<<dim3(4096), dim3(256),  0, stream>>>(adj, h, flags, bmp);
  k_wh   <<<dim3(256),  dim3(1024), 0, stream>>>(h, Wh, bWh, a_src, a_dst, a_b, flags,
                                                 Bp1, ssrc1, sdst1);
  if (big) {
    k_att1s<<<dim3(256), dim3(1024), 0, stream>>>(bmp, ssrc1, sdst1, (const short8*)Bp1,
                                                  part, partl);
    k_wo   <<<dim3(256), dim3(1024), 0, stream>>>(x2, part, partl, Wo, bWo, ao_src, ao_dst,
                                                  ao_b, flags, Bp2, ssrc2, sdst2);
  } else {
    k_att1 <<<dim3(256), dim3(1024), 0, stream>>>(bmp, ssrc1, sdst1, (const short8*)Bp1, x2);
    k_wo   <<<dim3(256), dim3(1024), 0, stream>>>(x2, (const float*)nullptr,
                                                  (const float*)nullptr, Wo, bWo, ao_src,
                                                  ao_dst, ao_b, flags, Bp2, ssrc2, sdst2);
  }
  k_att2 <<<dim3(256),  dim3(1024), 0, stream>>>(bmp, ssrc2, sdst2, (const short8*)Bp2,
                                                 flags, d_out);
}

// Round 12
// 183.292 us; speedup vs baseline: 1.8534x; 1.0174x over previous
//
#include <hip/hip_runtime.h>

#define NN 4096
#define NHEADS 4
#define HID 64
#define INDIM 256
#define LOG2E 1.4426950408889634f

using short8 = __attribute__((ext_vector_type(8))) short;
using f32x4  = __attribute__((ext_vector_type(4))) float;
using f32x2  = __attribute__((ext_vector_type(2))) float;

union f32u { float f; unsigned int u; };
union i4s8 { int4 i; short8 s; };

__device__ __forceinline__ float bf2f(unsigned short s) {
  f32u x; x.u = ((unsigned int)s) << 16; return x.f;
}
__device__ __forceinline__ unsigned short f2bf(float f) {
  f32u x; x.f = f;
  unsigned int r = x.u + 0x7fffu + ((x.u >> 16) & 1u);
  return (unsigned short)(r >> 16);
}
// packed f32x2 -> bf16x2 (RNE, same as f2bf) in one instruction
__device__ __forceinline__ unsigned int cvtpk(float lo, float hi) {
  unsigned int r;
  asm("v_cvt_pk_bf16_f32 %0, %1, %2" : "=v"(r) : "v"(lo), "v"(hi));
  return r;
}

// overloaded external-input loaders
__device__ __forceinline__ float ld(const unsigned short* p, size_t i) { return bf2f(p[i]); }
__device__ __forceinline__ float ld(const float* p, size_t i) { return p[i]; }
// 4-element loader (8B for bf16, 16B for fp32) — p must be 4-elem aligned
__device__ __forceinline__ void ld4(const unsigned short* p, float* out) {
  short4 v = *(const short4*)p;
  out[0] = bf2f((unsigned short)v.x); out[1] = bf2f((unsigned short)v.y);
  out[2] = bf2f((unsigned short)v.z); out[3] = bf2f((unsigned short)v.w);
}
__device__ __forceinline__ void ld4(const float* p, float* out) {
  float4 a = *(const float4*)p;
  out[0] = a.x; out[1] = a.y; out[2] = a.z; out[3] = a.w;
}

// ---------------- K0: adj -> bitmask bytes bm[i][j>>3]; dtype probe folded in.
__global__ __launch_bounds__(256) void k_bm(const void* adjv, const void* hv,
                                            int* __restrict__ flags,
                                            unsigned char* __restrict__ bm) {
  __shared__ int s_at;
  const int tid = threadIdx.x;
  if (tid == 0) s_at = 0;
  __syncthreads();
  const unsigned int* au = (const unsigned int*)adjv;
  unsigned int wv = au[tid];
  if ((wv & 0xFFFFu) == 0x3F80u) atomicOr(&s_at, 2);       // bf16 pair (1.0, x)
  else if (wv == 0x3F800000u) atomicOr(&s_at, 1);          // float32 1.0
  __syncthreads();
  const int at = (s_at & 2) ? 2 : (s_at & 1);
  const int i = blockIdx.x;
  if (i == 0 && tid < 64) {
    const unsigned short* hu = (const unsigned short*)hv;
    int bad = 0;
    for (int t = tid; t < 256; t += 64) {
      float v = bf2f(hu[t]);
      if (!(v > -1000.f && v < 1000.f)) bad = 1;           // fp32 halves look huge as bf16
    }
    unsigned long long m = __ballot(bad);
    if (tid == 0) { flags[0] = m ? 0 : 1; flags[1] = at; }
  }
#pragma unroll
  for (int rep = 0; rep < 2; rep++) {
    int jb = tid + rep * 256;
    unsigned int b = 0;
    if (at == 0) {
      const int4* arow = (const int4*)((const int*)adjv + (size_t)i * NN);
      int4 a0 = arow[jb * 2 + 0];
      int4 a1 = arow[jb * 2 + 1];
      b |= (a0.x > 0) ? 1u : 0u;  b |= (a0.y > 0) ? 2u : 0u;
      b |= (a0.z > 0) ? 4u : 0u;  b |= (a0.w > 0) ? 8u : 0u;
      b |= (a1.x > 0) ? 16u : 0u; b |= (a1.y > 0) ? 32u : 0u;
      b |= (a1.z > 0) ? 64u : 0u; b |= (a1.w > 0) ? 128u : 0u;
    } else if (at == 1) {
      const float* arow = (const float*)adjv + (size_t)i * NN + jb * 8;
      for (int t = 0; t < 8; t++) b |= (arow[t] > 0.5f) ? (1u << t) : 0u;
    } else {
      const unsigned short* arow = (const unsigned short*)adjv + (size_t)i * NN + jb * 8;
      for (int t = 0; t < 8; t++) b |= (bf2f(arow[t]) > 0.5f) ? (1u << t) : 0u;
    }
    bm[(size_t)i * 512 + jb] = (unsigned char)b;
  }
}

// ---------------- K1: wh = h@Wh + bWh. LDS-staged h tile (16x256), 16 waves =
// 4 heads x 4 k-quarters, two-slot LDS combine, pack phase writes int4 Bp1 units.
// ssrc/sdst pre-scaled by LOG2E so attention kernels use exp2 directly.
template <typename T>
__device__ __forceinline__ void wh_body(const T* h, const T* Wh, const T* bWh,
    const T* a_src, const T* a_dst, const T* a_b,
    unsigned short* __restrict__ Bp1, float* __restrict__ ssrc1, float* __restrict__ sdst1,
    float (*hs)[260], float (*wp)[16][260], float* av0, float* av1) {
  const int tid = threadIdx.x;
  const int w = tid >> 6, lane = tid & 63;
  const int head = w & 3, kq = w >> 2;
  const int rb = blockIdx.x;       // 0..255, 16 rows each
  const int R0 = rb * 16;
  const int d = lane;
  {
    const int r = tid >> 6, c4 = (tid & 63) * 4;
    float hv4[4];
    ld4(h + (size_t)(R0 + r) * 256 + c4, hv4);
    hs[r][c4 + 0] = hv4[0]; hs[r][c4 + 1] = hv4[1];
    hs[r][c4 + 2] = hv4[2]; hs[r][c4 + 3] = hv4[3];
  }
  if (tid < 256) av0[tid] = ld(a_src, tid);
  else if (tid < 512) av1[tid - 256] = ld(a_dst, tid - 256);
  __syncthreads();
  float acc[16];
  float bv = (kq == 0) ? ld(bWh, head * 64 + d) : 0.f;
#pragma unroll
  for (int r = 0; r < 16; r++) acc[r] = bv;
  const int k0 = kq * 64;
  for (int kb = 0; kb < 8; kb++) {
    float wv[8];
#pragma unroll
    for (int j = 0; j < 8; j++)
      wv[j] = ld(Wh, (size_t)(head * 256 + k0 + kb * 8 + j) * 64 + d);
#pragma unroll
    for (int r = 0; r < 16; r++) {
      float4 ha = *(const float4*)(&hs[r][k0 + kb * 8]);
      float4 hb = *(const float4*)(&hs[r][k0 + kb * 8 + 4]);
      acc[r] = fmaf(ha.x, wv[0], acc[r]);
      acc[r] = fmaf(ha.y, wv[1], acc[r]);
      acc[r] = fmaf(ha.z, wv[2], acc[r]);
      acc[r] = fmaf(ha.w, wv[3], acc[r]);
      acc[r] = fmaf(hb.x, wv[4], acc[r]);
      acc[r] = fmaf(hb.y, wv[5], acc[r]);
      acc[r] = fmaf(hb.z, wv[6], acc[r]);
      acc[r] = fmaf(hb.w, wv[7], acc[r]);
    }
  }
  if (kq >= 2) {
#pragma unroll
    for (int r = 0; r < 16; r++) wp[kq - 2][r][head * 64 + d] = acc[r];
  }
  __syncthreads();
  if (kq < 2) {
#pragma unroll
    for (int r = 0; r < 16; r++) wp[kq][r][head * 64 + d] += acc[r];
  }
  __syncthreads();
  if (tid < 512) {
    const int hh = tid >> 7, tt = (tid >> 5) & 3, lnh = tid & 31;
    const int q2 = (rb & 1) * 2 + (lnh >> 4);
    const int ln = q2 * 16 + (lnh & 15);
    const int dd = tt * 16 + (lnh & 15);
    const int rbase = (lnh >> 4) * 8;
    float v[8];
#pragma unroll
    for (int jj = 0; jj < 8; jj++)
      v[jj] = wp[0][rbase + jj][hh * 64 + dd] + wp[1][rbase + jj][hh * 64 + dd];
    i4s8 s;
    s.i.x = cvtpk(v[0], v[1]); s.i.y = cvtpk(v[2], v[3]);
    s.i.z = cvtpk(v[4], v[5]); s.i.w = cvtpk(v[6], v[7]);
    const int kb = rb >> 1;
    *(int4*)(Bp1 + ((((size_t)hh * 128 + kb) * 4 + tt) * 64 + ln) * 8) = s.i;
  } else if (tid < 576) {
    const int t2 = tid - 512;
    const int hh = t2 >> 4, r = t2 & 15;
    float ps = 0.f, pd = 0.f;
    for (int c = 0; c < 64; c++) {
      float wv2 = wp[0][r][hh * 64 + c] + wp[1][r][hh * 64 + c];
      ps = fmaf(wv2, av0[hh * 64 + c], ps);
      pd = fmaf(wv2, av1[hh * 64 + c], pd);
    }
    ssrc1[hh * NN + R0 + r] = (ps + ld(a_b, hh)) * LOG2E;
    sdst1[hh * NN + R0 + r] = pd * LOG2E;
  }
}
__global__ __launch_bounds__(1024, 4) void k_wh(const void* h, const void* Wh, const void* bWh,
    const void* a_src, const void* a_dst, const void* a_b, const int* __restrict__ flags,
    unsigned short* Bp1, float* ssrc1, float* sdst1) {
  __shared__ float hs[16][260];
  __shared__ float wp[2][16][260];
  __shared__ float av0[256], av1[256];
  if (flags[0])
    wh_body<unsigned short>((const unsigned short*)h, (const unsigned short*)Wh,
        (const unsigned short*)bWh, (const unsigned short*)a_src,
        (const unsigned short*)a_dst, (const unsigned short*)a_b, Bp1, ssrc1, sdst1,
        hs, wp, av0, av1);
  else
    wh_body<float>((const float*)h, (const float*)Wh, (const float*)bWh, (const float*)a_src,
        (const float*)a_dst, (const float*)a_b, Bp1, ssrc1, sdst1, hs, wp, av0, av1);
}

// ---------------- K2: layer-1 attention. Grid 256 = 128 rowblocks(32 rows) x 2 kb-halves.
// 1024 thr = 16 waves = 4 heads x 4 slices(16 kb). Two A-frags/wave share every B load.
// Score math packed as f32x2 pairs so LLVM can emit v_pk_add/mul_f32 (VALU-bound: 62%).
__global__ __launch_bounds__(1024, 4) void k_att1s(
    const unsigned char* __restrict__ bm, const float* __restrict__ ssrc,
    const float* __restrict__ sdst, const short8* __restrict__ Bp,
    float* __restrict__ part, float* __restrict__ partl) {
  const int rb = blockIdx.x & 127;
  const int half = blockIdx.x >> 7;
  const int tid = threadIdx.x;
  const int w = tid >> 6;
  const int head = w & 3;
  const int sl = w >> 2;  // 0..3: 16-kb slice within this half
  const int lane = tid & 63;
  const int r15 = lane & 15, quad = lane >> 4;
  const int row0 = rb * 32 + r15;
  const int row1 = row0 + 16;
  const float si0 = ssrc[head * NN + row0];
  const float si1 = ssrc[head * NN + row1];
  const f32x2 sp0 = {si0, si0};
  const f32x2 sp1 = {si1, si1};
  const unsigned char* bmr0 = bm + (size_t)row0 * 512;
  const unsigned char* bmr1 = bm + (size_t)row1 * 512;
  const float* sd = sdst + head * NN;
  const short8* Bh = Bp + (size_t)head * 128 * 4 * 64;
  f32x4 acc0[4], acc1[4];
#pragma unroll
  for (int t = 0; t < 4; t++) { acc0[t] = (f32x4){0,0,0,0}; acc1[t] = (f32x4){0,0,0,0}; }
  f32x2 l0 = {0.f, 0.f}, l1 = {0.f, 0.f};
  const int kb0 = half * 64 + sl * 16;
  for (int g = 0; g < 4; g++) {          // 4 kb per group, bm fetched as int4
    const int kbg = kb0 + g * 4;
    int4 u0 = *(const int4*)(bmr0 + kbg * 4);
    int4 u1 = *(const int4*)(bmr1 + kbg * 4);
    int wd0[4] = {u0.x, u0.y, u0.z, u0.w};
    int wd1[4] = {u1.x, u1.y, u1.z, u1.w};
#pragma unroll
    for (int kk = 0; kk < 4; kk++) {
      const int kb = kbg + kk;
      const int j0 = kb * 32 + quad * 8;
      float4 q0 = *(const float4*)(sd + j0);
      float4 q1 = *(const float4*)(sd + j0 + 4);
      f32x2 sd2[4];
      sd2[0] = (f32x2){q0.x, q0.y}; sd2[1] = (f32x2){q0.z, q0.w};
      sd2[2] = (f32x2){q1.x, q1.y}; sd2[3] = (f32x2){q1.z, q1.w};
      unsigned int bits0 = (((unsigned int)wd0[kk]) >> (quad * 8)) & 0xffu;
      unsigned int bits1 = (((unsigned int)wd1[kk]) >> (quad * 8)) & 0xffu;
      float pe0[8], pe1[8];
#pragma unroll
      for (int jp = 0; jp < 4; jp++) {
        f32x2 ta = sp0 + sd2[jp];          // v_pk_add_f32
        f32x2 tb = sp1 + sd2[jp];
        f32x2 ta5 = ta * 0.2f;             // v_pk_mul_f32
        f32x2 tb5 = tb * 0.2f;
        float ea0 = exp2f(fmaxf(ta[0], ta5[0]));
        float ea1 = exp2f(fmaxf(ta[1], ta5[1]));
        float eb0 = exp2f(fmaxf(tb[0], tb5[0]));
        float eb1 = exp2f(fmaxf(tb[1], tb5[1]));
        float pa0 = ((bits0 >> (2 * jp)) & 1u) ? ea0 : 0.f;
        float pa1 = ((bits0 >> (2 * jp + 1)) & 1u) ? ea1 : 0.f;
        float pb0 = ((bits1 >> (2 * jp)) & 1u) ? eb0 : 0.f;
        float pb1 = ((bits1 >> (2 * jp + 1)) & 1u) ? eb1 : 0.f;
        l0 += (f32x2){pa0, pa1};           // v_pk_add_f32
        l1 += (f32x2){pb0, pb1};
        pe0[2 * jp] = pa0; pe0[2 * jp + 1] = pa1;
        pe1[2 * jp] = pb0; pe1[2 * jp + 1] = pb1;
      }
      i4s8 a0, a1;
      a0.i.x = cvtpk(pe0[0], pe0[1]); a0.i.y = cvtpk(pe0[2], pe0[3]);
      a0.i.z = cvtpk(pe0[4], pe0[5]); a0.i.w = cvtpk(pe0[6], pe0[7]);
      a1.i.x = cvtpk(pe1[0], pe1[1]); a1.i.y = cvtpk(pe1[2], pe1[3]);
      a1.i.z = cvtpk(pe1[4], pe1[5]); a1.i.w = cvtpk(pe1[6], pe1[7]);
      const short8* Bk = Bh + (size_t)kb * 256 + lane;
      short8 bt[4];
      bt[0] = Bk[0]; bt[1] = Bk[64]; bt[2] = Bk[128]; bt[3] = Bk[192];
#pragma unroll
      for (int t = 0; t < 4; t++) {
        acc0[t] = __builtin_amdgcn_mfma_f32_16x16x32_bf16(a0.s, bt[t], acc0[t], 0, 0, 0);
        acc1[t] = __builtin_amdgcn_mfma_f32_16x16x32_bf16(a1.s, bt[t], acc1[t], 0, 0, 0);
      }
    }
  }
  float ls0 = l0[0] + l0[1];
  float ls1 = l1[0] + l1[1];
  ls0 += __shfl_xor(ls0, 16); ls0 += __shfl_xor(ls0, 32);
  ls1 += __shfl_xor(ls1, 16); ls1 += __shfl_xor(ls1, 32);
  __shared__ float accs[8][16][66];
  __shared__ float lsh[8][16];
#define DOPASS(AC, LSV, PASS)                                                  \
  do {                                                                         \
    if (sl >= 2) {                                                             \
      const int slot = head * 2 + (sl - 2);                                    \
      if (lane < 16) lsh[slot][lane] = (LSV);                                  \
      _Pragma("unroll") for (int t = 0; t < 4; t++)                            \
        _Pragma("unroll") for (int gg = 0; gg < 4; gg++)                       \
          accs[slot][quad * 4 + gg][t * 16 + r15] = (AC)[t][gg];               \
    }                                                                          \
    __syncthreads();                                                           \
    if (sl < 2) {                                                              \
      const int slot = head * 2 + sl;                                          \
      if (lane < 16) lsh[slot][lane] += (LSV);                                 \
      _Pragma("unroll") for (int t = 0; t < 4; t++)                            \
        _Pragma("unroll") for (int gg = 0; gg < 4; gg++)                       \
          accs[slot][quad * 4 + gg][t * 16 + r15] += (AC)[t][gg];              \
    }                                                                          \
    __syncthreads();                                                           \
    _Pragma("unroll") for (int idx = tid; idx < 4096; idx += 1024) {           \
      int r = idx >> 8, hc = idx & 255;                                        \
      int hh = hc >> 6, col = hc & 63;                                         \
      part[((size_t)half * NN + rb * 32 + (PASS) * 16 + r) * 256 + hc] =       \
          accs[hh * 2][r][col] + accs[hh * 2 + 1][r][col];                     \
    }                                                                          \
    if (tid < 64)                                                              \
      partl[((size_t)half * 4 + (tid >> 4)) * NN + rb * 32 + (PASS) * 16 +     \
            (tid & 15)] = lsh[(tid >> 4) * 2][tid & 15] +                      \
                          lsh[(tid >> 4) * 2 + 1][tid & 15];                   \
    __syncthreads();                                                           \
  } while (0)
  DOPASS(acc0, ls0, 0);
  DOPASS(acc1, ls1, 1);
#undef DOPASS
}

// ---------------- K2-old (fallback if workspace too small for partials)
__global__ __launch_bounds__(1024) void k_att1(
    const unsigned char* __restrict__ bm, const float* __restrict__ ssrc,
    const float* __restrict__ sdst, const short8* __restrict__ Bp,
    unsigned short* __restrict__ x2) {
  const int rb = blockIdx.x;
  const int tid = threadIdx.x;
  const int w = tid >> 6;
  const int head = w & 3;
  const int slice = w >> 2;
  const int lane = tid & 63;
  const int r15 = lane & 15, quad = lane >> 4;
  const int row = rb * 16 + r15;
  const float si = ssrc[head * NN + row];
  const unsigned char* bmrow = bm + (size_t)row * 512;
  const float* sd = sdst + head * NN;
  const short8* Bh = Bp + (size_t)head * 128 * 4 * 64;
  f32x4 acc0 = {0, 0, 0, 0}, acc1 = {0, 0, 0, 0}, acc2 = {0, 0, 0, 0}, acc3 = {0, 0, 0, 0};
  float lsum = 0.f;
  const int kb0 = slice * 32;
  for (int kb = kb0; kb < kb0 + 32; kb++) {
    const int j0 = kb * 32 + quad * 8;
    unsigned int bits = bmrow[kb * 4 + quad];
    float4 q0 = *(const float4*)(sd + j0);
    float4 q1 = *(const float4*)(sd + j0 + 4);
    float sdv[8] = {q0.x, q0.y, q0.z, q0.w, q1.x, q1.y, q1.z, q1.w};
    short8 af;
#pragma unroll
    for (int jj = 0; jj < 8; jj++) {
      float t = si + sdv[jj];
      float lr = fmaxf(t, 0.2f * t);
      float e = exp2f(lr);
      float pe = ((bits >> jj) & 1u) ? e : 0.0f;
      lsum += pe;
      af[jj] = (short)f2bf(pe);
    }
    const short8* Bk = Bh + (size_t)kb * 256 + lane;
    short8 b0 = Bk[0], b1 = Bk[64], b2 = Bk[128], b3 = Bk[192];
    acc0 = __builtin_amdgcn_mfma_f32_16x16x32_bf16(af, b0, acc0, 0, 0, 0);
    acc1 = __builtin_amdgcn_mfma_f32_16x16x32_bf16(af, b1, acc1, 0, 0, 0);
    acc2 = __builtin_amdgcn_mfma_f32_16x16x32_bf16(af, b2, acc2, 0, 0, 0);
    acc3 = __builtin_amdgcn_mfma_f32_16x16x32_bf16(af, b3, acc3, 0, 0, 0);
  }
  lsum += __shfl_xor(lsum, 16);
  lsum += __shfl_xor(lsum, 32);
  __shared__ float accs[8][16][66];
  __shared__ float ls[8][16];
  if (slice >= 2) {
    const int slot = w - 8;
    if (lane < 16) ls[slot][lane] = lsum;
#pragma unroll
    for (int g = 0; g < 4; g++) {
      int r = quad * 4 + g;
      accs[slot][r][ 0 + r15] = acc0[g];
      accs[slot][r][16 + r15] = acc1[g];
      accs[slot][r][32 + r15] = acc2[g];
      accs[slot][r][48 + r15] = acc3[g];
    }
  }
  __syncthreads();
  if (slice < 2) {
    const int slot = w;
    if (lane < 16) ls[slot][lane] += lsum;
#pragma unroll
    for (int g = 0; g < 4; g++) {
      int r = quad * 4 + g;
      accs[slot][r][ 0 + r15] += acc0[g];
      accs[slot][r][16 + r15] += acc1[g];
      accs[slot][r][32 + r15] += acc2[g];
      accs[slot][r][48 + r15] += acc3[g];
    }
  }
  __syncthreads();
#pragma unroll
  for (int c = tid; c < 4096; c += 1024) {
    int r = c >> 8, hc = c & 255;
    int hh = hc >> 6, col = hc & 63;
    float s = accs[hh][r][col] + accs[hh + 4][r][col];
    float lt = ls[hh][r] + ls[hh + 4][r];
    float v = (lt > 0.f) ? s / lt : 0.f;
    v = v > 0.f ? v : __expf(v) - 1.f;
    x2[(size_t)(rb * 16 + r) * 256 + hc] = f2bf(v);
  }
}

// ---------------- K3: wo = x2@Wo + bWo. Big path stages from 2-half part/partl
// (half-sum + normalize + elu inline); fallback path (part==nullptr) stages from x2.
template <typename T>
__device__ __forceinline__ void wo_body(const unsigned short* x2,
    const float* part, const float* partl,
    const T* Wo, const T* bWo, const T* ao_src, const T* ao_dst, const T* ao_b,
    unsigned short* __restrict__ Bp2, float* __restrict__ ssrc2, float* __restrict__ sdst2,
    float (*xs)[260], float (*wp)[16][68], float* av) {
  const int tid = threadIdx.x;
  const int w = tid >> 6, lane = tid & 63;
  const int rg = w & 3, kq = w >> 2;
  const int rb = blockIdx.x;         // 0..255, 16 rows each
  const int d = lane;
  {
    const int r = tid >> 6, c4 = (tid & 63) * 4;
    const int row = rb * 16 + r;
    if (part) {
      float4 p0 = *(const float4*)(part + (size_t)row * 256 + c4);
      float4 p1 = *(const float4*)(part + (size_t)NN * 256 + (size_t)row * 256 + c4);
      const int head = c4 >> 6;
      float lt = partl[(size_t)head * NN + row] + partl[(size_t)(4 + head) * NN + row];
      float rl = (lt > 0.f) ? 1.f / lt : 0.f;
      float v0 = (p0.x + p1.x) * rl, v1 = (p0.y + p1.y) * rl;
      float v2 = (p0.z + p1.z) * rl, v3 = (p0.w + p1.w) * rl;
      v0 = v0 > 0.f ? v0 : __expf(v0) - 1.f;
      v1 = v1 > 0.f ? v1 : __expf(v1) - 1.f;
      v2 = v2 > 0.f ? v2 : __expf(v2) - 1.f;
      v3 = v3 > 0.f ? v3 : __expf(v3) - 1.f;
      xs[r][c4 + 0] = v0; xs[r][c4 + 1] = v1;
      xs[r][c4 + 2] = v2; xs[r][c4 + 3] = v3;
    } else {
      float hv4[4];
      ld4(x2 + (size_t)row * 256 + c4, hv4);
      xs[r][c4 + 0] = hv4[0]; xs[r][c4 + 1] = hv4[1];
      xs[r][c4 + 2] = hv4[2]; xs[r][c4 + 3] = hv4[3];
    }
  }
  if (tid < 64) av[tid] = ld(ao_src, tid);
  else if (tid < 128) av[tid] = ld(ao_dst, tid - 64);
  __syncthreads();
  const int rr = rg * 4;             // this wave's 4 local rows
  float acc[4];
  float bv = (kq == 0) ? ld(bWo, d) : 0.f;
#pragma unroll
  for (int r = 0; r < 4; r++) acc[r] = bv;
  const int k0 = kq * 64;
  for (int kb = 0; kb < 8; kb++) {
    float wv[8];
#pragma unroll
    for (int j = 0; j < 8; j++)
      wv[j] = ld(Wo, (size_t)(k0 + kb * 8 + j) * 64 + d);
#pragma unroll
    for (int r = 0; r < 4; r++) {
      float4 ha = *(const float4*)(&xs[rr + r][k0 + kb * 8]);
      float4 hb = *(const float4*)(&xs[rr + r][k0 + kb * 8 + 4]);
      acc[r] = fmaf(ha.x, wv[0], acc[r]);
      acc[r] = fmaf(ha.y, wv[1], acc[r]);
      acc[r] = fmaf(ha.z, wv[2], acc[r]);
      acc[r] = fmaf(ha.w, wv[3], acc[r]);
      acc[r] = fmaf(hb.x, wv[4], acc[r]);
      acc[r] = fmaf(hb.y, wv[5], acc[r]);
      acc[r] = fmaf(hb.z, wv[6], acc[r]);
      acc[r] = fmaf(hb.w, wv[7], acc[r]);
    }
  }
  if (kq >= 2) {
#pragma unroll
    for (int r = 0; r < 4; r++) wp[kq - 2][rr + r][d] = acc[r];
  }
  __syncthreads();
  if (kq < 2) {
#pragma unroll
    for (int r = 0; r < 4; r++) wp[kq][rr + r][d] += acc[r];
  }
  __syncthreads();
  if (tid < 128) {
    const int tt = tid >> 5, lnh = tid & 31;
    const int q2 = (rb & 1) * 2 + (lnh >> 4);
    const int ln = q2 * 16 + (lnh & 15);
    const int dd = tt * 16 + (lnh & 15);
    const int rbase = (lnh >> 4) * 8;
    float v[8];
#pragma unroll
    for (int jj = 0; jj < 8; jj++)
      v[jj] = wp[0][rbase + jj][dd] + wp[1][rbase + jj][dd];
    i4s8 s;
    s.i.x = cvtpk(v[0], v[1]); s.i.y = cvtpk(v[2], v[3]);
    s.i.z = cvtpk(v[4], v[5]); s.i.w = cvtpk(v[6], v[7]);
    const int kb = rb >> 1;
    *(int4*)(Bp2 + (((size_t)kb * 4 + tt) * 64 + ln) * 8) = s.i;
  } else if (tid < 144) {
    const int r = tid - 128;
    float ps = 0.f, pd = 0.f;
    for (int c = 0; c < 64; c++) {
      float wv2 = wp[0][r][c] + wp[1][r][c];
      ps = fmaf(wv2, av[c], ps);
      pd = fmaf(wv2, av[64 + c], pd);
    }
    ssrc2[(size_t)rb * 16 + r] = (ps + ld(ao_b, 0)) * LOG2E;
    sdst2[(size_t)rb * 16 + r] = pd * LOG2E;
  }
}
__global__ __launch_bounds__(1024, 4) void k_wo(const unsigned short* __restrict__ x2,
    const float* __restrict__ part, const float* __restrict__ partl,
    const void* Wo, const void* bWo, const void* ao_src, const void* ao_dst, const void* ao_b,
    const int* __restrict__ flags, unsigned short* Bp2, float* ssrc2, float* sdst2) {
  __shared__ float xs[16][260];
  __shared__ float wp[2][16][68];
  __shared__ float av[128];
  if (flags[0])
    wo_body<unsigned short>(x2, part, partl, (const unsigned short*)Wo,
        (const unsigned short*)bWo, (const unsigned short*)ao_src,
        (const unsigned short*)ao_dst, (const unsigned short*)ao_b,
        Bp2, ssrc2, sdst2, xs, wp, av);
  else
    wo_body<float>(x2, part, partl, (const float*)Wo, (const float*)bWo,
        (const float*)ao_src, (const float*)ao_dst, (const float*)ao_b,
        Bp2, ssrc2, sdst2, xs, wp, av);
}

// ---------------- K4: layer-2 attention (1 head), 16 rows/block, 16-way j-split.
// Score math packed as f32x2 pairs (same as k_att1s).
__global__ __launch_bounds__(1024) void k_att2(
    const unsigned char* __restrict__ bm, const float* __restrict__ ssrc,
    const float* __restrict__ sdst, const short8* __restrict__ Bp,
    const int* __restrict__ flags, void* __restrict__ outv) {
  const int rb = blockIdx.x;
  const int tid = threadIdx.x;
  const int w = tid >> 6;  // j-slice 0..15
  const int lane = tid & 63;
  const int r15 = lane & 15, quad = lane >> 4;
  const int row = rb * 16 + r15;
  const float si = ssrc[row];
  const f32x2 sp = {si, si};
  const unsigned char* bmrow = bm + (size_t)row * 512;
  f32x4 acc0 = {0, 0, 0, 0}, acc1 = {0, 0, 0, 0}, acc2 = {0, 0, 0, 0}, acc3 = {0, 0, 0, 0};
  f32x2 lp = {0.f, 0.f};
  const int kb0 = w * 8;
#pragma unroll
  for (int g = 0; g < 2; g++) {
    int4 ubm = *(const int4*)(bmrow + (kb0 + g * 4) * 4);
    int wds[4] = {ubm.x, ubm.y, ubm.z, ubm.w};
#pragma unroll
    for (int kk = 0; kk < 4; kk++) {
      const int kb = kb0 + g * 4 + kk;
      const int j0 = kb * 32 + quad * 8;
      unsigned int bits = (((unsigned int)wds[kk]) >> (quad * 8)) & 0xffu;
      float4 q0 = *(const float4*)(sdst + j0);
      float4 q1 = *(const float4*)(sdst + j0 + 4);
      f32x2 sd2[4];
      sd2[0] = (f32x2){q0.x, q0.y}; sd2[1] = (f32x2){q0.z, q0.w};
      sd2[2] = (f32x2){q1.x, q1.y}; sd2[3] = (f32x2){q1.z, q1.w};
      float pe[8];
#pragma unroll
      for (int jp = 0; jp < 4; jp++) {
        f32x2 t = sp + sd2[jp];            // v_pk_add_f32
        f32x2 t5 = t * 0.2f;               // v_pk_mul_f32
        float e0 = exp2f(fmaxf(t[0], t5[0]));
        float e1 = exp2f(fmaxf(t[1], t5[1]));
        float p0 = ((bits >> (2 * jp)) & 1u) ? e0 : 0.f;
        float p1 = ((bits >> (2 * jp + 1)) & 1u) ? e1 : 0.f;
        lp += (f32x2){p0, p1};             // v_pk_add_f32
        pe[2 * jp] = p0; pe[2 * jp + 1] = p1;
      }
      i4s8 a;
      a.i.x = cvtpk(pe[0], pe[1]); a.i.y = cvtpk(pe[2], pe[3]);
      a.i.z = cvtpk(pe[4], pe[5]); a.i.w = cvtpk(pe[6], pe[7]);
      const short8* Bk = Bp + (size_t)kb * 256 + lane;
      short8 b0 = Bk[0], b1 = Bk[64], b2 = Bk[128], b3 = Bk[192];
      acc0 = __builtin_amdgcn_mfma_f32_16x16x32_bf16(a.s, b0, acc0, 0, 0, 0);
      acc1 = __builtin_amdgcn_mfma_f32_16x16x32_bf16(a.s, b1, acc1, 0, 0, 0);
      acc2 = __builtin_amdgcn_mfma_f32_16x16x32_bf16(a.s, b2, acc2, 0, 0, 0);
      acc3 = __builtin_amdgcn_mfma_f32_16x16x32_bf16(a.s, b3, acc3, 0, 0, 0);
    }
  }
  float lsum = lp[0] + lp[1];
  lsum += __shfl_xor(lsum, 16);
  lsum += __shfl_xor(lsum, 32);
  __shared__ float accs[8][16][66];
  __shared__ float ls2[8][16];
  if (w >= 8) {
    const int slot = w - 8;
    if (lane < 16) ls2[slot][lane] = lsum;
#pragma unroll
    for (int g = 0; g < 4; g++) {
      int r = quad * 4 + g;
      accs[slot][r][ 0 + r15] = acc0[g];
      accs[slot][r][16 + r15] = acc1[g];
      accs[slot][r][32 + r15] = acc2[g];
      accs[slot][r][48 + r15] = acc3[g];
    }
  }
  __syncthreads();
  if (w < 8) {
    const int slot = w;
    if (lane < 16) ls2[slot][lane] += lsum;
#pragma unroll
    for (int g = 0; g < 4; g++) {
      int r = quad * 4 + g;
      accs[slot][r][ 0 + r15] += acc0[g];
      accs[slot][r][16 + r15] += acc1[g];
      accs[slot][r][32 + r15] += acc2[g];
      accs[slot][r][48 + r15] += acc3[g];
    }
  }
  __syncthreads();
  {
    const int r = tid >> 6, col = tid & 63;
    float s = 0.f, lt = 0.f;
#pragma unroll
    for (int k = 0; k < 8; k++) { s += accs[k][r][col]; lt += ls2[k][r]; }
    float v = (lt > 0.f) ? s / lt : 0.f;
    v = v > 0.f ? v : __expf(v) - 1.f;
    size_t idx = (size_t)(rb * 16 + r) * 64 + col;
    if (flags[0]) ((unsigned short*)outv)[idx] = f2bf(v);
    else          ((float*)outv)[idx] = v;
  }
}

extern "C" void kernel_launch(void* const* d_in, const int* in_sizes, int n_in,
                              void* d_out, int out_size, void* d_ws, size_t ws_size,
                              hipStream_t stream) {
  const void* h      = d_in[0];
  const void* adj    = d_in[1];
  const void* Wh     = d_in[2];
  const void* bWh    = d_in[3];
  const void* a_src  = d_in[4];
  const void* a_dst  = d_in[5];
  const void* a_b    = d_in[6];
  const void* Wo     = d_in[7];
  const void* bWo    = d_in[8];
  const void* ao_src = d_in[9];
  const void* ao_dst = d_in[10];
  const void* ao_b   = d_in[11];

  size_t need_old = 16 + (size_t)NN * 512 + (size_t)NHEADS * NN * HID * 2 +
                    (size_t)NN * 256 * 2 + (size_t)NN * 64 * 2 +
                    (size_t)NHEADS * NN * 8 + (size_t)NN * 8;
  size_t need_new = need_old + (size_t)2 * NN * 256 * 4 + (size_t)2 * 4 * NN * 4;
  if (ws_size < need_old) {
    // Distinct signature if workspace is too small (bf16 0x4545 = 789).
    hipMemsetAsync(d_out, 0x45, (size_t)out_size * 2, stream);
    return;
  }
  const bool big = ws_size >= need_new;
  unsigned char* ws = (unsigned char*)d_ws;
  int* flags = (int*)ws;                        ws += 16;
  unsigned char* bmp = ws;                      ws += (size_t)NN * 512;               // 2 MB
  unsigned short* Bp1 = (unsigned short*)ws;    ws += (size_t)NHEADS * NN * HID * 2;  // 2 MB
  unsigned short* x2  = (unsigned short*)ws;    ws += (size_t)NN * 256 * 2;           // 2 MB
  unsigned short* Bp2 = (unsigned short*)ws;    ws += (size_t)NN * 64 * 2;            // 512 KB
  float* ssrc1 = (float*)ws;                    ws += (size_t)NHEADS * NN * 4;
  float* sdst1 = (float*)ws;                    ws += (size_t)NHEADS * NN * 4;
  float* ssrc2 = (float*)ws;                    ws += (size_t)NN * 4;
  float* sdst2 = (float*)ws;                    ws += (size_t)NN * 4;
  float* part  = (float*)ws;                    ws += (size_t)2 * NN * 256 * 4;       // 8 MB
  float* partl = (float*)ws;                    ws += (size_t)2 * 4 * NN * 4;         // 128 KB

  k_bm   <<<dim3(4096), dim3(256),  0, stream>>>(adj, h, flags, bmp);
  k_wh   <<<dim3(256),  dim3(1024), 0, stream>>>(h, Wh, bWh, a_src, a_dst, a_b, flags,
                                                 Bp1, ssrc1, sdst1);
  if (big) {
    k_att1s<<<dim3(256), dim3(1024), 0, stream>>>(bmp, ssrc1, sdst1, (const short8*)Bp1,
                                                  part, partl);
    k_wo   <<<dim3(256), dim3(1024), 0, stream>>>(x2, part, partl, Wo, bWo, ao_src, ao_dst,
                                                  ao_b, flags, Bp2, ssrc2, sdst2);
  } else {
    k_att1 <<<dim3(256), dim3(1024), 0, stream>>>(bmp, ssrc1, sdst1, (const short8*)Bp1, x2);
    k_wo   <<<dim3(256), dim3(1024), 0, stream>>>(x2, (const float*)nullptr,
                                                  (const float*)nullptr, Wo, bWo, ao_src,
                                                  ao_dst, ao_b, flags, Bp2, ssrc2, sdst2);
  }
  k_att2 <<<dim3(256),  dim3(1024), 0, stream>>>(bmp, ssrc2, sdst2, (const short8*)Bp2,
                                                 flags, d_out);
}